// Round 4
// baseline (1028.862 us; speedup 1.0000x reference)
//
#include <hip/hip_runtime.h>
#include <math.h>

#define EPS 1e-5f

typedef __attribute__((ext_vector_type(8))) short short8;
typedef __attribute__((ext_vector_type(4))) float f32x4;

__device__ __forceinline__ short f2bf(float f) {
    unsigned u = __float_as_uint(f);
    u += 0x7fffu + ((u >> 16) & 1u);
    return (short)(u >> 16);
}
__device__ __forceinline__ float bf2f(short s) {
    return __uint_as_float(((unsigned)(unsigned short)s) << 16);
}
__device__ __forceinline__ void async16(const void* g, void* l) {
    __builtin_amdgcn_global_load_lds(
        (const __attribute__((address_space(1))) unsigned*)g,
        (__attribute__((address_space(3))) unsigned*)l, 16, 0, 0);
}

// ---------------------------------------------------------------------------
// Agent-scope (cross-XCD coherent) load/store helpers. All cross-WG data in
// mega goes through these, so barriers need NO cache flush/invalidate.
// ---------------------------------------------------------------------------
__device__ __forceinline__ unsigned long long aldu(const void* p) {
    return __hip_atomic_load((const unsigned long long*)p, __ATOMIC_RELAXED,
                             __HIP_MEMORY_SCOPE_AGENT);
}
__device__ __forceinline__ void astu(void* p, unsigned long long v) {
    __hip_atomic_store((unsigned long long*)p, v, __ATOMIC_RELAXED,
                       __HIP_MEMORY_SCOPE_AGENT);
}
__device__ __forceinline__ float2 ald2(const float* p) {
    unsigned long long u = aldu(p);
    float2 f;
    f.x = __uint_as_float((unsigned)u);
    f.y = __uint_as_float((unsigned)(u >> 32));
    return f;
}
__device__ __forceinline__ float ald1(const float* p) {
    return __uint_as_float(__hip_atomic_load((const unsigned*)p, __ATOMIC_RELAXED,
                                             __HIP_MEMORY_SCOPE_AGENT));
}
__device__ __forceinline__ void ast1(float* p, float v) {
    __hip_atomic_store((unsigned*)p, __float_as_uint(v), __ATOMIC_RELAXED,
                       __HIP_MEMORY_SCOPE_AGENT);
}

// ---------------------------------------------------------------------------
// Per-group barrier (32 WGs now). Release fetch_add + relaxed polling.
// ---------------------------------------------------------------------------
__device__ __forceinline__ void group_sync(unsigned* flag, unsigned goal) {
    __syncthreads();
    if (threadIdx.x == 0) {
        __hip_atomic_fetch_add(flag, 1u, __ATOMIC_RELEASE, __HIP_MEMORY_SCOPE_AGENT);
        unsigned spins = 0;
        while (__hip_atomic_load(flag, __ATOMIC_RELAXED, __HIP_MEMORY_SCOPE_AGENT) < goal) {
            __builtin_amdgcn_s_sleep(1);
            if (++spins > 2000000u) break;   // deadlock bailout
        }
    }
    __syncthreads();
}

// ---------------------------------------------------------------------------
__device__ __forceinline__ float block_reduce_sum_256(float v, float* red) {
    #pragma unroll
    for (int o = 32; o > 0; o >>= 1) v += __shfl_down(v, o, 64);
    __syncthreads();
    if ((threadIdx.x & 63) == 0) red[threadIdx.x >> 6] = v;
    __syncthreads();
    return red[0] + red[1] + red[2] + red[3];
}

// ---------------------------------------------------------------------------
// prep_all: unchanged except it zeroes the 512-entry flag array.
__global__ __launch_bounds__(256) void prep_all(
    const float* __restrict__ z, const float* __restrict__ fw,
    const float* __restrict__ fb, float* __restrict__ gb,
    const float* __restrict__ conv_w, short* __restrict__ wbf,
    const float* __restrict__ x, short* __restrict__ xbf,
    float* __restrict__ ropeS, float* __restrict__ ropeC,
    const float* __restrict__ kqv_w, short* __restrict__ kqvT,
    const float* __restrict__ proj_w, short* __restrict__ projT,
    const float* __restrict__ mlp_w1, short* __restrict__ mlp1T,
    const float* __restrict__ mlp_w2, short* __restrict__ mlp2T,
    unsigned* __restrict__ bar) {
    int bi = blockIdx.x, tid = threadIdx.x;
    if (bi == 0) { bar[tid] = 0u; bar[tid + 256] = 0u; }
    if (bi < 512) {
        __shared__ float zs[32];
        if (tid < 32) zs[tid] = z[bi * 32 + tid];
        __syncthreads();
        for (int j = tid; j < 1024; j += 256) {
            float acc = fb[j];
            #pragma unroll
            for (int k = 0; k < 32; k++) acc = fmaf(zs[k], fw[k * 1024 + j], acc);
            gb[bi * 1024 + j] = acc;
        }
        return;
    }
    if (bi < 1664) {
        int i = (bi - 512) * 256 + tid;
        wbf[i] = f2bf(conv_w[i]);
        return;
    }
    if (bi < 4736) {
        int i = (bi - 1664) * 256 + tid;
        float4 a = *(const float4*)(x + (size_t)i * 8);
        float4 b = *(const float4*)(x + (size_t)i * 8 + 4);
        short8 o = {f2bf(a.x), f2bf(a.y), f2bf(a.z), f2bf(a.w),
                    f2bf(b.x), f2bf(b.y), f2bf(b.z), f2bf(b.w)};
        *(short8*)(xbf + (size_t)i * 8) = o;
        return;
    }
    if (bi < 4740) {
        int idx = (bi - 4736) * 256 + tid;
        if (idx < 1024) {
            int t = idx >> 5, j = idx & 31;
            float ang = (float)t * expf(-(float)j * (logf(10000.f) / 32.f));
            ropeS[idx] = sinf(ang);
            ropeC[idx] = cosf(ang);
        }
        return;
    }
    __shared__ float tile[32][33];
    int rel0 = bi - 4740;
    const float* src; short* dst; int NT, K, N, rel;
    if (rel0 < 4608)       { src = kqv_w;  dst = kqvT;  NT = 48; K = 512;  N = 1536; rel = rel0; }
    else if (rel0 < 6144)  { src = proj_w; dst = projT; NT = 16; K = 512;  N = 512;  rel = rel0 - 4608; }
    else if (rel0 < 12288) { src = mlp_w1; dst = mlp1T; NT = 64; K = 512;  N = 2048; rel = rel0 - 6144; }
    else                   { src = mlp_w2; dst = mlp2T; NT = 16; K = 2048; N = 512;  rel = rel0 - 12288; }
    int per = NT * (K / 32);
    int layer = rel / per, r2 = rel - layer * per;
    int nt = r2 % NT, kt = r2 / NT;
    src += (size_t)layer * K * N;
    dst += (size_t)layer * N * K;
    int n0 = nt * 32, k0 = kt * 32;
    int lx = tid & 31, ly = tid >> 5;
    #pragma unroll
    for (int i = 0; i < 32; i += 8)
        tile[ly + i][lx] = src[(size_t)(k0 + ly + i) * N + n0 + lx];
    __syncthreads();
    if (tid < 128) {
        int row = tid >> 2, c = tid & 3;
        short8 o;
        #pragma unroll
        for (int j = 0; j < 8; j++) o[j] = f2bf(tile[c * 8 + j][row]);
        *(short8*)(dst + (size_t)(n0 + row) * K + k0 + c * 8) = o;
    }
}

// ---------------------------------------------------------------------------
// conv_fused: unchanged.
__global__ __launch_bounds__(256, 2) void conv_fused(
    const short* __restrict__ xbf, const short* __restrict__ wbf,
    const float* __restrict__ cb, const float* __restrict__ tg,
    const float* __restrict__ tb, const float* __restrict__ gb,
    float* __restrict__ h) {
    __shared__ short As[64 * 32];
    __shared__ short Bs[512 * 32];
    __shared__ float redsum[4][64], redss[4][64];
    __shared__ float mu_s[64], inv_s[64];
    int bt = blockIdx.x, b = bt >> 5, t = bt & 31;
    int tid = threadIdx.x;
    int wave = tid >> 6, lane = tid & 63, quad = lane >> 4, l16 = lane & 15;

    int rowA = tid >> 2;
    int cA = (tid & 3) ^ ((rowA >> 1) & 3);
    int hn = rowA >> 3, wn2 = rowA & 7;
    long long baseA = (((long long)(b * 32 + t - 2) * 3) << 12)
                      + (long long)(hn * 8) * 64 + wn2 * 8;

    f32x4 acc[4][8];
    #pragma unroll
    for (int mt = 0; mt < 4; mt++)
        #pragma unroll
        for (int nt = 0; nt < 8; nt++) acc[mt][nt] = (f32x4){0.f, 0.f, 0.f, 0.f};

    for (int k0 = 0; k0 < 576; k0 += 32) {
        #pragma unroll
        for (int e = 0; e < 8; e++) {
            int s = e * 256 + tid;
            int n = s >> 2;
            int c = (s & 3) ^ ((n >> 1) & 3);
            async16(wbf + (size_t)n * 576 + k0 + c * 8, Bs + s * 8);
        }
        {
            int ks = (k0 >> 3) + cA;
            int ch = (ks >= 24) + (ks >= 48);
            int r = ks - ch * 24;
            int kt = r >> 3, ph = r & 7;
            short8 v8 = (short8){0, 0, 0, 0, 0, 0, 0, 0};
            if (t + kt >= 2)
                v8 = *(const short8*)(xbf + baseA
                        + ((long long)(kt * 3 + ch) << 12) + ph * 64);
            *(short8*)(As + tid * 8) = v8;
        }
        __syncthreads();
        short8 af[4], bf[8];
        #pragma unroll
        for (int mt = 0; mt < 4; mt++) {
            int row = mt * 16 + l16;
            int pc = quad ^ ((row >> 1) & 3);
            af[mt] = *(const short8*)(As + row * 32 + pc * 8);
        }
        #pragma unroll
        for (int nt = 0; nt < 8; nt++) {
            int row = wave * 128 + nt * 16 + l16;
            int pc = quad ^ ((row >> 1) & 3);
            bf[nt] = *(const short8*)(Bs + row * 32 + pc * 8);
        }
        #pragma unroll
        for (int mt = 0; mt < 4; mt++)
            #pragma unroll
            for (int nt = 0; nt < 8; nt++)
                acc[mt][nt] = __builtin_amdgcn_mfma_f32_16x16x32_bf16(
                    af[mt], bf[nt], acc[mt][nt], 0, 0, 0);
        __syncthreads();
    }

    float cbn[8], tgn[8], tbn[8], Gn[8], Ben[8];
    #pragma unroll
    for (int nt = 0; nt < 8; nt++) {
        int n = wave * 128 + nt * 16 + l16;
        cbn[nt] = cb[n]; tgn[nt] = tg[n]; tbn[nt] = tb[n];
        Gn[nt]  = 1.f + 0.5f * gb[bt * 1024 + n];
        Ben[nt] = 0.5f * gb[bt * 1024 + 512 + n];
    }
    #pragma unroll
    for (int mt = 0; mt < 4; mt++)
        #pragma unroll
        for (int reg = 0; reg < 4; reg++) {
            float s = 0.f, ss = 0.f;
            #pragma unroll
            for (int nt = 0; nt < 8; nt++) {
                float v = acc[mt][nt][reg] + cbn[nt];
                s += v; ss += v * v;
            }
            #pragma unroll
            for (int o = 1; o < 16; o <<= 1) {
                s  += __shfl_xor(s, o, 64);
                ss += __shfl_xor(ss, o, 64);
            }
            if (l16 == 0) {
                int m = mt * 16 + quad * 4 + reg;
                redsum[wave][m] = s; redss[wave][m] = ss;
            }
        }
    __syncthreads();
    if (tid < 64) {
        float S  = redsum[0][tid] + redsum[1][tid] + redsum[2][tid] + redsum[3][tid];
        float SS = redss[0][tid] + redss[1][tid] + redss[2][tid] + redss[3][tid];
        float mu = S * (1.f / 512.f);
        float var = SS * (1.f / 512.f) - mu * mu;
        mu_s[tid] = mu; inv_s[tid] = rsqrtf(var + EPS);
    }
    __syncthreads();
    float hacc[8] = {0.f, 0.f, 0.f, 0.f, 0.f, 0.f, 0.f, 0.f};
    #pragma unroll
    for (int mt = 0; mt < 4; mt++)
        #pragma unroll
        for (int reg = 0; reg < 4; reg++) {
            int m = mt * 16 + quad * 4 + reg;
            float mu = mu_s[m], inv = inv_s[m];
            #pragma unroll
            for (int nt = 0; nt < 8; nt++) {
                float v = acc[mt][nt][reg] + cbn[nt];
                hacc[nt] += (v - mu) * inv;
            }
        }
    #pragma unroll
    for (int nt = 0; nt < 8; nt++) {
        hacc[nt] += __shfl_xor(hacc[nt], 16, 64);
        hacc[nt] += __shfl_xor(hacc[nt], 32, 64);
    }
    if (quad == 0)
        #pragma unroll
        for (int nt = 0; nt < 8; nt++) {
            int n = wave * 128 + nt * 16 + l16;
            h[bt * 512 + n] = Gn[nt] * (tgn[nt] * (hacc[nt] * (1.f / 64.f)) + tbn[nt])
                              + Ben[nt];
        }
}

// ---------------------------------------------------------------------------
// P1: attn for one (batch g, head hh). Body identical to round 3 except the
// k0=0 B-prefetch is hoisted to the very top (overlaps LN pass 1).
// ---------------------------------------------------------------------------
__device__ __forceinline__ void attn_phase(
    char* smem, int g, int hh, int tid,
    const float* __restrict__ hsrc, const float* __restrict__ lng,
    const float* __restrict__ lnb, const short* __restrict__ Bw,
    const float* __restrict__ bias, const float* __restrict__ ropeS,
    const float* __restrict__ ropeC, short* __restrict__ yv) {
    float* mu_s = (float*)(smem + 65536);
    float* inv_s = (float*)(smem + 65664);
    short* As = (short*)smem;                      // 32 KB
    short* BsB[2] = {(short*)(smem + 32768), (short*)(smem + 45056)};  // 12 KB ea
    float (*qsf)[64] = (float(*)[64])(smem);
    float (*ksf)[64] = (float(*)[64])(smem + 8192);
    short* vT  = (short*)(smem + 16384);
    short* qrb = (short*)(smem + 20480);
    short* krb = (short*)(smem + 24576);
    float (*att)[33] = (float(*)[33])(smem + 28672);
    short* pA  = (short*)(smem + 36864);
    short* yv_s = (short*)(smem + 28672);          // 32x64 bf16 (after softmax)
    int m0 = g * 32;
    // early prefetch of B k0=0 (hoisted: overlaps LN pass 1)
    #pragma unroll
    for (int e = 0; e < 3; e++) {
        int p = e * 256 + tid;
        int row = p >> 2, seg = (p & 3) ^ ((row >> 1) & 3);
        int n = ((row >> 6) << 9) + hh * 64 + (row & 63);
        async16(Bw + (size_t)n * 512 + seg * 8, BsB[0] + p * 8);
    }
    // LN pass 1 (sc1)
    {
        int row = tid >> 3, l8 = tid & 7;
        const float* hp = hsrc + (size_t)(m0 + row) * 512 + l8 * 64;
        float s = 0.f, ss = 0.f;
        #pragma unroll
        for (int i = 0; i < 32; i++) {
            float2 v = ald2(hp + i * 2);
            s += v.x + v.y;
            ss += v.x * v.x + v.y * v.y;
        }
        s += __shfl_xor(s, 1, 64); ss += __shfl_xor(ss, 1, 64);
        s += __shfl_xor(s, 2, 64); ss += __shfl_xor(ss, 2, 64);
        s += __shfl_xor(s, 4, 64); ss += __shfl_xor(ss, 4, 64);
        if (l8 == 0) {
            float mu = s * (1.f / 512.f);
            float var = ss * (1.f / 512.f) - mu * mu;
            mu_s[row] = mu;
            inv_s[row] = rsqrtf(var + EPS);
        }
    }
    __syncthreads();
    // LN pass 2 -> As (sc1)
    #pragma unroll
    for (int e = 0; e < 8; e++) {
        int lc = e * 256 + tid;
        int row = lc >> 6, cc = lc & 63;
        float mu = mu_s[row], inv = inv_s[row];
        const float* hp = hsrc + (size_t)(m0 + row) * 512 + cc * 8;
        float2 p0 = ald2(hp), p1 = ald2(hp + 2), p2 = ald2(hp + 4), p3 = ald2(hp + 6);
        float4 g0 = *(const float4*)(lng + cc * 8), g1 = *(const float4*)(lng + cc * 8 + 4);
        float4 b0 = *(const float4*)(lnb + cc * 8), b1 = *(const float4*)(lnb + cc * 8 + 4);
        short8 o = {f2bf((p0.x - mu) * inv * g0.x + b0.x),
                    f2bf((p0.y - mu) * inv * g0.y + b0.y),
                    f2bf((p1.x - mu) * inv * g0.z + b0.z),
                    f2bf((p1.y - mu) * inv * g0.w + b0.w),
                    f2bf((p2.x - mu) * inv * g1.x + b1.x),
                    f2bf((p2.y - mu) * inv * g1.y + b1.y),
                    f2bf((p3.x - mu) * inv * g1.z + b1.z),
                    f2bf((p3.y - mu) * inv * g1.w + b1.w)};
        *(short8*)(As + (row * 64 + (cc ^ (row & 7))) * 8) = o;
    }
    __syncthreads();
    int wave = tid >> 6, lane = tid & 63, quad = lane >> 4, l16 = lane & 15;
    f32x4 acc[2][3];
    #pragma unroll
    for (int m2 = 0; m2 < 2; m2++)
        #pragma unroll
        for (int gg = 0; gg < 3; gg++) acc[m2][gg] = (f32x4){0.f, 0.f, 0.f, 0.f};
    for (int it = 0; it < 16; it++) {
        short* Bsc = BsB[it & 1];
        if (it < 15) {
            int k0n = (it + 1) * 32;
            short* Bsn = BsB[(it + 1) & 1];
            #pragma unroll
            for (int e = 0; e < 3; e++) {
                int p = e * 256 + tid;
                int row = p >> 2, seg = (p & 3) ^ ((row >> 1) & 3);
                int n = ((row >> 6) << 9) + hh * 64 + (row & 63);
                async16(Bw + (size_t)n * 512 + k0n + seg * 8, Bsn + p * 8);
            }
        }
        int cc = it * 4 + quad;
        short8 af[2], bf[3];
        #pragma unroll
        for (int m2 = 0; m2 < 2; m2++) {
            int row = m2 * 16 + l16;
            af[m2] = *(const short8*)(As + (row * 64 + (cc ^ (row & 7))) * 8);
        }
        #pragma unroll
        for (int gg = 0; gg < 3; gg++) {
            int row = gg * 64 + wave * 16 + l16;
            int pc = quad ^ ((row >> 1) & 3);
            bf[gg] = *(const short8*)(Bsc + (row * 4 + pc) * 8);
        }
        #pragma unroll
        for (int m2 = 0; m2 < 2; m2++)
            #pragma unroll
            for (int gg = 0; gg < 3; gg++)
                acc[m2][gg] = __builtin_amdgcn_mfma_f32_16x16x32_bf16(
                    af[m2], bf[gg], acc[m2][gg], 0, 0, 0);
        __syncthreads();
    }
    // epilogue: k,q fp32 -> LDS; v -> vT bf16
    float bb0 = bias[hh * 64 + wave * 16 + l16];
    float bb1 = bias[512 + hh * 64 + wave * 16 + l16];
    float bb2 = bias[1024 + hh * 64 + wave * 16 + l16];
    int dcol = wave * 16 + l16;
    #pragma unroll
    for (int m2 = 0; m2 < 2; m2++)
        #pragma unroll
        for (int reg = 0; reg < 4; reg++) {
            int tkn = m2 * 16 + quad * 4 + reg;
            ksf[tkn][dcol] = acc[m2][0][reg] + bb0;
            qsf[tkn][dcol] = acc[m2][1][reg] + bb1;
            vT[dcol * 32 + (((tkn >> 3) ^ (dcol & 3)) << 3) + (tkn & 7)]
                = f2bf(acc[m2][2][reg] + bb2);
        }
    __syncthreads();
    // RoPE (table)
    #pragma unroll
    for (int e = 0; e < 8; e++) {
        int idx = e * 256 + tid;
        int t = idx >> 6, d = idx & 63, j = d & 31;
        float sv = ropeS[t * 32 + j], cv = ropeC[t * 32 + j];
        float qv = qsf[t][d], kv = ksf[t][d];
        float qo = qsf[t][d ^ 32], ko = ksf[t][d ^ 32];
        float rq = (d < 32) ? -qo : qo;
        float rk = (d < 32) ? -ko : ko;
        int addr = t * 64 + (((d >> 3) ^ (t & 7)) << 3) + (d & 7);
        qrb[addr] = f2bf(qv * cv + rq * sv);
        krb[addr] = f2bf(kv * cv + rk * sv);
    }
    __syncthreads();
    int mw = wave & 1, nw = wave >> 1;
    // QK^T via MFMA
    {
        f32x4 sc = (f32x4){0.f, 0.f, 0.f, 0.f};
        #pragma unroll
        for (int kc = 0; kc < 2; kc++) {
            int rq = mw * 16 + l16;
            int rk = nw * 16 + l16;
            short8 aq = *(const short8*)(qrb + rq * 64 + ((((kc << 2) + quad) ^ (rq & 7)) << 3));
            short8 bk = *(const short8*)(krb + rk * 64 + ((((kc << 2) + quad) ^ (rk & 7)) << 3));
            sc = __builtin_amdgcn_mfma_f32_16x16x32_bf16(aq, bk, sc, 0, 0, 0);
        }
        #pragma unroll
        for (int reg = 0; reg < 4; reg++) {
            int qt = mw * 16 + quad * 4 + reg;
            int kt = nw * 16 + l16;
            att[qt][kt] = (kt > qt) ? -1e30f : sc[reg] * 0.125f;
        }
    }
    __syncthreads();
    // softmax
    {
        int row = tid >> 3, gg = tid & 7;
        float v0 = att[row][gg * 4], v1 = att[row][gg * 4 + 1];
        float v2 = att[row][gg * 4 + 2], v3 = att[row][gg * 4 + 3];
        float mx = fmaxf(fmaxf(v0, v1), fmaxf(v2, v3));
        mx = fmaxf(mx, __shfl_xor(mx, 1, 64));
        mx = fmaxf(mx, __shfl_xor(mx, 2, 64));
        mx = fmaxf(mx, __shfl_xor(mx, 4, 64));
        float e0 = expf(v0 - mx), e1 = expf(v1 - mx);
        float e2 = expf(v2 - mx), e3 = expf(v3 - mx);
        float s = e0 + e1 + e2 + e3;
        s += __shfl_xor(s, 1, 64);
        s += __shfl_xor(s, 2, 64);
        s += __shfl_xor(s, 4, 64);
        float inv = 1.f / s;
        short* pp = pA + row * 32 + gg * 4;
        pp[0] = f2bf(e0 * inv); pp[1] = f2bf(e1 * inv);
        pp[2] = f2bf(e2 * inv); pp[3] = f2bf(e3 * inv);
    }
    __syncthreads();
    // PV via MFMA -> stage to LDS
    {
        int rp = mw * 16 + l16;
        short8 ap = *(const short8*)(pA + rp * 32 + quad * 8);
        #pragma unroll
        for (int i = 0; i < 2; i++) {
            int nt = (wave >> 1) * 2 + i;
            int rv = nt * 16 + l16;
            short8 bv = *(const short8*)(vT + rv * 32 + (((quad ^ (rv & 3))) << 3));
            f32x4 o = (f32x4){0.f, 0.f, 0.f, 0.f};
            o = __builtin_amdgcn_mfma_f32_16x16x32_bf16(ap, bv, o, 0, 0, 0);
            #pragma unroll
            for (int reg = 0; reg < 4; reg++) {
                int t = mw * 16 + quad * 4 + reg;
                int d = nt * 16 + l16;
                yv_s[t * 64 + d] = f2bf(o[reg]);
            }
        }
    }
    __syncthreads();
    // cooperative sc1 store of the 32x64 slice
    #pragma unroll
    for (int e = 0; e < 2; e++) {
        int idx = e * 256 + tid;
        int t = idx >> 4, c = idx & 15;
        astu(yv + (size_t)(m0 + t) * 512 + hh * 64 + c * 4,
             *(const unsigned long long*)(yv_s + t * 64 + c * 4));
    }
}

// ---------------------------------------------------------------------------
// P2: proj + gated residual (16 active WGs/group, 32-col slices). Unchanged.
// ---------------------------------------------------------------------------
__device__ __forceinline__ void proj_phase(
    char* smem, int g, int wgl, int tid,
    const float* __restrict__ hA, const short* __restrict__ yv,
    const short* __restrict__ Bw, const float* __restrict__ bias,
    const float* __restrict__ rsPtr, float* __restrict__ hB) {
    short* As = (short*)smem;               // 32KB
    short* Bs = (short*)(smem + 32768);     // 32KB
    int m0 = g * 32, n0 = wgl * 32;
    #pragma unroll
    for (int e = 0; e < 8; e++) {
        int p = e * 256 + tid;
        int row = p >> 6, c = p & 63;
        int cl = c ^ (row & 7);
        async16(Bw + (size_t)(n0 + row) * 512 + cl * 8, Bs + p * 8);
    }
    #pragma unroll
    for (int e = 0; e < 8; e++) {
        int p = e * 256 + tid;
        int row = p >> 6, c = p & 63;
        const short* src = yv + (size_t)(m0 + row) * 512 + c * 8;
        unsigned long long a = aldu(src), b = aldu(src + 4);
        short* d = As + (row * 64 + (c ^ (row & 7))) * 8;
        *(unsigned long long*)d = a;
        *(unsigned long long*)(d + 4) = b;
    }
    __syncthreads();
    int wave = tid >> 6, lane = tid & 63, quad = lane >> 4, l16 = lane & 15;
    int mw = wave & 1, nw = wave >> 1;
    f32x4 acc = (f32x4){0.f, 0.f, 0.f, 0.f};
    #pragma unroll
    for (int kk = 0; kk < 16; kk++) {
        int cc = kk * 4 + quad;
        int ra = mw * 16 + l16, rb = nw * 16 + l16;
        short8 af = *(const short8*)(As + (ra * 64 + (cc ^ (ra & 7))) * 8);
        short8 bf = *(const short8*)(Bs + (rb * 64 + (cc ^ (rb & 7))) * 8);
        acc = __builtin_amdgcn_mfma_f32_16x16x32_bf16(af, bf, acc, 0, 0, 0);
    }
    float rsv = *rsPtr;
    #pragma unroll
    for (int reg = 0; reg < 4; reg++) {
        int m = m0 + mw * 16 + quad * 4 + reg;
        int n = n0 + nw * 16 + l16;
        float base = ald1(hA + (size_t)m * 512 + n);
        float v = base + rsv * (acc[reg] + bias[n]);
        ast1(hB + (size_t)m * 512 + n, v);
    }
}

// ---------------------------------------------------------------------------
// P3: LN2 + mlp1 + GELU -> mb (32 active WGs/group, 64-col slices). Also
// zeroes this group's hA slice (P4's atomicAdd target).
// ---------------------------------------------------------------------------
__device__ __forceinline__ void mlp1_phase(
    char* smem, int g, int wgl, int tid,
    const float* __restrict__ hB, const float* __restrict__ lng,
    const float* __restrict__ lnb, const short* __restrict__ Bw,
    const float* __restrict__ bias, short* __restrict__ mb,
    float* __restrict__ hA) {
    short* As = (short*)smem;                // 32KB
    short* Bs = (short*)(smem + 32768);      // 16KB (64 rows x 128k)
    float* mu_s = (float*)(smem + 65536);
    float* inv_s = (float*)(smem + 65664);
    int m0 = g * 32, n0 = wgl * 64;
    // B prefetch k0=0 (hoisted to top)
    #pragma unroll
    for (int e = 0; e < 4; e++) {
        int p = e * 256 + tid;
        int row = p >> 4, seg = (p & 15) ^ (row & 15);
        async16(Bw + (size_t)(n0 + row) * 512 + seg * 8, Bs + p * 8);
    }
    // zero hA slice (32 WGs x 512 floats)
    {
        float* za = hA + (size_t)m0 * 512 + wgl * 512 + tid * 2;
        astu(za, 0ull);
    }
    // LN pass1 (sc1)
    {
        int row = tid >> 3, l8 = tid & 7;
        const float* hp = hB + (size_t)(m0 + row) * 512 + l8 * 64;
        float s = 0.f, ss = 0.f;
        #pragma unroll
        for (int i = 0; i < 32; i++) {
            float2 v = ald2(hp + i * 2);
            s += v.x + v.y;
            ss += v.x * v.x + v.y * v.y;
        }
        s += __shfl_xor(s, 1, 64); ss += __shfl_xor(ss, 1, 64);
        s += __shfl_xor(s, 2, 64); ss += __shfl_xor(ss, 2, 64);
        s += __shfl_xor(s, 4, 64); ss += __shfl_xor(ss, 4, 64);
        if (l8 == 0) {
            float mu = s * (1.f / 512.f);
            float var = ss * (1.f / 512.f) - mu * mu;
            mu_s[row] = mu;
            inv_s[row] = rsqrtf(var + EPS);
        }
    }
    __syncthreads();
    // LN pass2 -> As (sc1)
    #pragma unroll
    for (int e = 0; e < 8; e++) {
        int lc = e * 256 + tid;
        int row = lc >> 6, cc = lc & 63;
        float mu = mu_s[row], inv = inv_s[row];
        const float* hp = hB + (size_t)(m0 + row) * 512 + cc * 8;
        float2 p0 = ald2(hp), p1 = ald2(hp + 2), p2 = ald2(hp + 4), p3 = ald2(hp + 6);
        float4 g0 = *(const float4*)(lng + cc * 8), g1 = *(const float4*)(lng + cc * 8 + 4);
        float4 b0 = *(const float4*)(lnb + cc * 8), b1 = *(const float4*)(lnb + cc * 8 + 4);
        short8 o = {f2bf((p0.x - mu) * inv * g0.x + b0.x),
                    f2bf((p0.y - mu) * inv * g0.y + b0.y),
                    f2bf((p1.x - mu) * inv * g0.z + b0.z),
                    f2bf((p1.y - mu) * inv * g0.w + b0.w),
                    f2bf((p2.x - mu) * inv * g1.x + b1.x),
                    f2bf((p2.y - mu) * inv * g1.y + b1.y),
                    f2bf((p3.x - mu) * inv * g1.z + b1.z),
                    f2bf((p3.y - mu) * inv * g1.w + b1.w)};
        *(short8*)(As + (row * 64 + (cc ^ (row & 7))) * 8) = o;
    }
    __syncthreads();
    int wave = tid >> 6, lane = tid & 63, quad = lane >> 4, l16 = lane & 15;
    f32x4 acc[2];
    acc[0] = (f32x4){0.f, 0.f, 0.f, 0.f};
    acc[1] = (f32x4){0.f, 0.f, 0.f, 0.f};
    for (int it = 0; it < 4; it++) {
        int k0 = it * 128;
        #pragma unroll
        for (int ksub = 0; ksub < 4; ksub++) {
            int ccb = ksub * 4 + quad;
            int rowb = wave * 16 + l16;
            short8 bf = *(const short8*)(Bs + (rowb * 16 + (ccb ^ (rowb & 15))) * 8);
            #pragma unroll
            for (int m2 = 0; m2 < 2; m2++) {
                int row = m2 * 16 + l16;
                int cc = (k0 >> 3) + ccb;
                short8 af = *(const short8*)(As + (row * 64 + (cc ^ (row & 7))) * 8);
                acc[m2] = __builtin_amdgcn_mfma_f32_16x16x32_bf16(af, bf, acc[m2], 0, 0, 0);
            }
        }
        __syncthreads();
        if (it < 3) {
            int k0n = (it + 1) * 128;
            #pragma unroll
            for (int e = 0; e < 4; e++) {
                int p = e * 256 + tid;
                int row = p >> 4, seg = (p & 15) ^ (row & 15);
                async16(Bw + (size_t)(n0 + row) * 512 + k0n + seg * 8, Bs + p * 8);
            }
            __syncthreads();
        }
    }
    __syncthreads();
    // GELU -> stage into As region (dead) -> sc1 bulk store
    short* outS = As;   // 32x64 bf16 = 4KB
    #pragma unroll
    for (int m2 = 0; m2 < 2; m2++)
        #pragma unroll
        for (int reg = 0; reg < 4; reg++) {
            int mr = m2 * 16 + quad * 4 + reg;
            int nr = wave * 16 + l16;
            float v = acc[m2][reg] + bias[n0 + nr];
            v = 0.5f * v * (1.f + erff(v * 0.70710678118f));
            outS[mr * 64 + nr] = f2bf(v);
        }
    __syncthreads();
    #pragma unroll
    for (int e = 0; e < 2; e++) {
        int idx = e * 256 + tid;
        int m = idx >> 4, c = idx & 15;
        astu(mb + (size_t)(m0 + m) * 2048 + n0 + c * 4,
             *(const unsigned long long*)(outS + m * 64 + c * 4));
    }
}

// ---------------------------------------------------------------------------
// P4: mlp2 + gated residual into zeroed hA via atomicAdd. 32 WGs/group =
// 8 n-slices (64 cols) x 4 K-quarters (Ks=512). BK=128, double-buffered.
// ---------------------------------------------------------------------------
__device__ __forceinline__ void mlp2_phase(
    char* smem, int g, int wgl, int tid,
    const float* __restrict__ hB, const short* __restrict__ mb,
    const short* __restrict__ Bw, const float* __restrict__ bias,
    const float* __restrict__ rsPtr, float* __restrict__ hA) {
    short* As = (short*)smem;               // 2 x 8KB
    short* Bs = (short*)(smem + 16384);     // 2 x 16KB
    int kz = wgl & 3, nb = wgl >> 2;
    int m0 = g * 32, n0 = nb * 64, kbase = kz * 512;
    int wave = tid >> 6, lane = tid & 63, quad = lane >> 4, l16 = lane & 15;
    f32x4 acc[2];
    acc[0] = (f32x4){0.f, 0.f, 0.f, 0.f};
    acc[1] = (f32x4){0.f, 0.f, 0.f, 0.f};
    unsigned long long r0, r1, r2, r3;
    int rowA0 = tid >> 4, segA0 = (tid & 15) ^ (rowA0 & 15);
    int rowA1 = (256 + tid) >> 4, segA1 = ((256 + tid) & 15) ^ (rowA1 & 15);
    auto ldA = [&](int k0) {
        const short* s0 = mb + (size_t)(m0 + rowA0) * 2048 + k0 + segA0 * 8;
        const short* s1 = mb + (size_t)(m0 + rowA1) * 2048 + k0 + segA1 * 8;
        r0 = aldu(s0); r1 = aldu(s0 + 4);
        r2 = aldu(s1); r3 = aldu(s1 + 4);
    };
    auto wrA = [&](int buf) {
        *(unsigned long long*)(As + buf * 4096 + tid * 8) = r0;
        *(unsigned long long*)(As + buf * 4096 + tid * 8 + 4) = r1;
        *(unsigned long long*)(As + buf * 4096 + (256 + tid) * 8) = r2;
        *(unsigned long long*)(As + buf * 4096 + (256 + tid) * 8 + 4) = r3;
    };
    auto stB = [&](int k0, int buf) {
        #pragma unroll
        for (int e = 0; e < 4; e++) {
            int p = e * 256 + tid;
            int row = p >> 4, seg = (p & 15) ^ (row & 15);
            async16(Bw + (size_t)(n0 + row) * 2048 + k0 + seg * 8,
                    Bs + buf * 8192 + p * 8);
        }
    };
    ldA(kbase); stB(kbase, 0); wrA(0);
    __syncthreads();
    for (int it = 0; it < 4; it++) {
        int cur = it & 1;
        if (it < 3) { stB(kbase + (it + 1) * 128, cur ^ 1); ldA(kbase + (it + 1) * 128); }
        #pragma unroll
        for (int ksub = 0; ksub < 4; ksub++) {
            int ccb = ksub * 4 + quad;
            int rb = wave * 16 + l16;
            short8 bf = *(const short8*)(Bs + cur * 8192 + (rb * 16 + (ccb ^ (rb & 15))) * 8);
            #pragma unroll
            for (int m2 = 0; m2 < 2; m2++) {
                int ra = m2 * 16 + l16;
                short8 af = *(const short8*)(As + cur * 4096 + (ra * 16 + (ccb ^ (ra & 15))) * 8);
                acc[m2] = __builtin_amdgcn_mfma_f32_16x16x32_bf16(af, bf, acc[m2], 0, 0, 0);
            }
        }
        if (it < 3) wrA(cur ^ 1);
        __syncthreads();
    }
    float rsv = *rsPtr;
    #pragma unroll
    for (int m2 = 0; m2 < 2; m2++)
        #pragma unroll
        for (int reg = 0; reg < 4; reg++) {
            int m = m0 + m2 * 16 + quad * 4 + reg;
            int n = n0 + wave * 16 + l16;
            float v = rsv * (acc[m2][reg] + (kz == 0 ? bias[n] : 0.f));
            if (kz == 0) v += ald1(hB + (size_t)m * 512 + n);
            atomicAdd(&hA[(size_t)m * 512 + n], v);
        }
}

// ---------------------------------------------------------------------------
__device__ __forceinline__ void head_phase(
    char* smem, int token, int tid,
    const float* __restrict__ h, const float* __restrict__ g,
    const float* __restrict__ bb, const float* __restrict__ w,
    const float* __restrict__ bias0, float* __restrict__ out) {
    float* red = (float*)smem;
    float v0 = ald1(h + (size_t)token * 512 + tid);
    float v1 = ald1(h + (size_t)token * 512 + tid + 256);
    float s  = block_reduce_sum_256(v0 + v1, red);
    float ss = block_reduce_sum_256(v0 * v0 + v1 * v1, red);
    float mu = s * (1.f / 512.f);
    float var = ss * (1.f / 512.f) - mu * mu;
    float inv = rsqrtf(var + EPS);
    float n0 = (v0 - mu) * inv * g[tid] + bb[tid];
    float n1 = (v1 - mu) * inv * g[tid + 256] + bb[tid + 256];
    float dot = block_reduce_sum_256(n0 * w[tid] + n1 * w[tid + 256], red);
    if (tid == 0) out[token] = dot + bias0[0];
}

// ---------------------------------------------------------------------------
// mega v3: 16 group pipelines x 32 WGs = 512 WGs, 2 WGs/CU (launch_bounds
// (256,2), LDS 64.25KB <= 80KB). Full 256-CU coverage + 8 waves/CU so one
// WG's load stalls / barrier waits overlap the partner WG's compute.
// ---------------------------------------------------------------------------
__global__ __launch_bounds__(256, 2) void mega(
    float* __restrict__ hA, float* __restrict__ hB,
    short* __restrict__ yvb, short* __restrict__ mbuf,
    const float* __restrict__ ropeS, const float* __restrict__ ropeC,
    const short* __restrict__ kqvT, const short* __restrict__ projT,
    const short* __restrict__ mlp1T, const short* __restrict__ mlp2T,
    const float* __restrict__ ln1_g, const float* __restrict__ ln1_b,
    const float* __restrict__ kqv_b, const float* __restrict__ proj_b,
    const float* __restrict__ ln2_g, const float* __restrict__ ln2_b,
    const float* __restrict__ mlp_b1, const float* __restrict__ mlp_b2,
    const float* __restrict__ rs_attn, const float* __restrict__ rs_mlp,
    const float* __restrict__ head_g, const float* __restrict__ head_b,
    const float* __restrict__ head_w, const float* __restrict__ head_bs,
    float* __restrict__ out, unsigned* __restrict__ bar) {
    __shared__ char smem[65792] __attribute__((aligned(16)));
    int wg = blockIdx.x, tid = threadIdx.x;
    int g = wg >> 5, wgl = wg & 31;
    unsigned* flag = bar + g * 32;   // 128B spacing
    unsigned goal = 0;

    for (int i = 0; i < 6; i++) {
        // ---- P1: attn (8 head-WGs per group) ----
        if (wgl < 8)
            attn_phase(smem, g, wgl, tid, hA, ln1_g + i * 512, ln1_b + i * 512,
                       kqvT + (size_t)i * 786432, kqv_b + i * 1536,
                       ropeS, ropeC, yvb);
        goal += 32; group_sync(flag, goal);
        // ---- P2: proj + residual -> hB (16 WGs x 32-col slices) ----
        if (wgl < 16)
            proj_phase(smem, g, wgl, tid, hA, yvb,
                       projT + (size_t)i * 262144, proj_b + i * 512,
                       rs_attn + i, hB);
        goal += 32; group_sync(flag, goal);
        // ---- P3: LN2 + mlp1 + GELU -> mbuf (32 WGs x 64-col; zeroes hA) ----
        mlp1_phase(smem, g, wgl, tid, hB, ln2_g + i * 512, ln2_b + i * 512,
                   mlp1T + (size_t)i * 1048576, mlp_b1 + i * 2048, mbuf, hA);
        goal += 32; group_sync(flag, goal);
        // ---- P4: mlp2 + residual -> hA (32 WGs = 8n x 4kz, atomicAdd) ----
        mlp2_phase(smem, g, wgl, tid, hB, mbuf,
                   mlp2T + (size_t)i * 1048576, mlp_b2 + i * 512,
                   rs_mlp + i, hA);
        goal += 32; group_sync(flag, goal);
    }
    // ---- head: 1 token per WG (512 tokens) ----
    head_phase(smem, wg, tid, hA, head_g, head_b, head_w, head_bs, out);
}

// ---------------------------------------------------------------------------
extern "C" void kernel_launch(void* const* d_in, const int* in_sizes, int n_in,
                              void* d_out, int out_size, void* d_ws, size_t ws_size,
                              hipStream_t stream) {
    const float* x       = (const float*)d_in[0];
    const float* z       = (const float*)d_in[1];
    const float* conv_w  = (const float*)d_in[2];
    const float* conv_b  = (const float*)d_in[3];
    const float* tok_g   = (const float*)d_in[4];
    const float* tok_b   = (const float*)d_in[5];
    const float* film_w  = (const float*)d_in[6];
    const float* film_b  = (const float*)d_in[7];
    const float* ln1_g   = (const float*)d_in[8];
    const float* ln1_b   = (const float*)d_in[9];
    const float* kqv_w   = (const float*)d_in[10];
    const float* kqv_b   = (const float*)d_in[11];
    const float* proj_w  = (const float*)d_in[12];
    const float* proj_b  = (const float*)d_in[13];
    const float* ln2_g   = (const float*)d_in[14];
    const float* ln2_b   = (const float*)d_in[15];
    const float* mlp_w1  = (const float*)d_in[16];
    const float* mlp_b1  = (const float*)d_in[17];
    const float* mlp_w2  = (const float*)d_in[18];
    const float* mlp_b2  = (const float*)d_in[19];
    const float* rs_attn = (const float*)d_in[20];
    const float* rs_mlp  = (const float*)d_in[21];
    const float* head_g  = (const float*)d_in[22];
    const float* head_b  = (const float*)d_in[23];
    const float* head_w  = (const float*)d_in[24];
    const float* head_bs = (const float*)d_in[25];
    float* out = (float*)d_out;

    float* ws = (float*)d_ws;
    float* gb    = ws;                  // 524288 f  (FiLM; dead after conv -> hB)
    float* h     = gb + 524288;         // 262144 f  (hA)
    float* ropeS = h + 262144;          // 1024 f
    float* ropeC = ropeS + 1024;        // 1024 f
    short* sb = (short*)(ropeC + 1024);
    short* wbf   = sb;                 // 294912
    short* kqvT  = wbf   + 294912;     // 4718592
    short* projT = kqvT  + 4718592;    // 1572864
    short* mlp1T = projT + 1572864;    // 6291456
    short* mlp2T = mlp1T + 6291456;    // 6291456
    short* yvb   = mlp2T + 6291456;    // 262144
    short* mbuf  = yvb   + 262144;     // 1048576
    short* xbf   = mbuf  + 1048576;    // 6291456
    unsigned* bar = (unsigned*)(xbf + 6291456);   // 512 u32
    float* hB = gb;                    // reuse (1 MB needed of 2 MB)

    prep_all<<<23172, 256, 0, stream>>>(
        z, film_w, film_b, gb, conv_w, wbf, x, xbf, ropeS, ropeC,
        kqv_w, kqvT, proj_w, projT, mlp_w1, mlp1T, mlp_w2, mlp2T, bar);

    conv_fused<<<512, 256, 0, stream>>>(xbf, wbf, conv_b, tok_g, tok_b, gb, h);

    mega<<<512, 256, 0, stream>>>(
        h, hB, yvb, mbuf, ropeS, ropeC, kqvT, projT, mlp1T, mlp2T,
        ln1_g, ln1_b, kqv_b, proj_b, ln2_g, ln2_b, mlp_b1, mlp_b2,
        rs_attn, rs_mlp, head_g, head_b, head_w, head_bs, out, bar);
}

// Round 5
// 898.813 us; speedup vs baseline: 1.1447x; 1.1447x over previous
//
#include <hip/hip_runtime.h>
#include <math.h>

#define EPS 1e-5f

typedef __attribute__((ext_vector_type(8))) short short8;
typedef __attribute__((ext_vector_type(4))) float f32x4;

__device__ __forceinline__ short f2bf(float f) {
    unsigned u = __float_as_uint(f);
    u += 0x7fffu + ((u >> 16) & 1u);
    return (short)(u >> 16);
}
__device__ __forceinline__ float bf2f(short s) {
    return __uint_as_float(((unsigned)(unsigned short)s) << 16);
}
__device__ __forceinline__ void async16(const void* g, void* l) {
    __builtin_amdgcn_global_load_lds(
        (const __attribute__((address_space(1))) unsigned*)g,
        (__attribute__((address_space(3))) unsigned*)l, 16, 0, 0);
}

// ---------------------------------------------------------------------------
// Agent-scope (cross-XCD coherent) load/store helpers. All cross-WG data in
// mega goes through these, so barriers need NO cache flush/invalidate.
// ---------------------------------------------------------------------------
__device__ __forceinline__ unsigned long long aldu(const void* p) {
    return __hip_atomic_load((const unsigned long long*)p, __ATOMIC_RELAXED,
                             __HIP_MEMORY_SCOPE_AGENT);
}
__device__ __forceinline__ void astu(void* p, unsigned long long v) {
    __hip_atomic_store((unsigned long long*)p, v, __ATOMIC_RELAXED,
                       __HIP_MEMORY_SCOPE_AGENT);
}
__device__ __forceinline__ float2 ald2(const float* p) {
    unsigned long long u = aldu(p);
    float2 f;
    f.x = __uint_as_float((unsigned)u);
    f.y = __uint_as_float((unsigned)(u >> 32));
    return f;
}
__device__ __forceinline__ float ald1(const float* p) {
    return __uint_as_float(__hip_atomic_load((const unsigned*)p, __ATOMIC_RELAXED,
                                             __HIP_MEMORY_SCOPE_AGENT));
}
__device__ __forceinline__ void ast1(float* p, float v) {
    __hip_atomic_store((unsigned*)p, __float_as_uint(v), __ATOMIC_RELAXED,
                       __HIP_MEMORY_SCOPE_AGENT);
}

// ---------------------------------------------------------------------------
// Per-group barrier (32 WGs). Release fetch_add + relaxed polling.
// ---------------------------------------------------------------------------
__device__ __forceinline__ void group_sync(unsigned* flag, unsigned goal) {
    __syncthreads();
    if (threadIdx.x == 0) {
        __hip_atomic_fetch_add(flag, 1u, __ATOMIC_RELEASE, __HIP_MEMORY_SCOPE_AGENT);
        unsigned spins = 0;
        while (__hip_atomic_load(flag, __ATOMIC_RELAXED, __HIP_MEMORY_SCOPE_AGENT) < goal) {
            __builtin_amdgcn_s_sleep(1);
            if (++spins > 2000000u) break;   // deadlock bailout
        }
    }
    __syncthreads();
}

// ---------------------------------------------------------------------------
__device__ __forceinline__ float block_reduce_sum_256(float v, float* red) {
    #pragma unroll
    for (int o = 32; o > 0; o >>= 1) v += __shfl_down(v, o, 64);
    __syncthreads();
    if ((threadIdx.x & 63) == 0) red[threadIdx.x >> 6] = v;
    __syncthreads();
    return red[0] + red[1] + red[2] + red[3];
}

// ---------------------------------------------------------------------------
// prep_all: unchanged (zeroes the 512-entry flag array).
__global__ __launch_bounds__(256) void prep_all(
    const float* __restrict__ z, const float* __restrict__ fw,
    const float* __restrict__ fb, float* __restrict__ gb,
    const float* __restrict__ conv_w, short* __restrict__ wbf,
    const float* __restrict__ x, short* __restrict__ xbf,
    float* __restrict__ ropeS, float* __restrict__ ropeC,
    const float* __restrict__ kqv_w, short* __restrict__ kqvT,
    const float* __restrict__ proj_w, short* __restrict__ projT,
    const float* __restrict__ mlp_w1, short* __restrict__ mlp1T,
    const float* __restrict__ mlp_w2, short* __restrict__ mlp2T,
    unsigned* __restrict__ bar) {
    int bi = blockIdx.x, tid = threadIdx.x;
    if (bi == 0) { bar[tid] = 0u; bar[tid + 256] = 0u; }
    if (bi < 512) {
        __shared__ float zs[32];
        if (tid < 32) zs[tid] = z[bi * 32 + tid];
        __syncthreads();
        for (int j = tid; j < 1024; j += 256) {
            float acc = fb[j];
            #pragma unroll
            for (int k = 0; k < 32; k++) acc = fmaf(zs[k], fw[k * 1024 + j], acc);
            gb[bi * 1024 + j] = acc;
        }
        return;
    }
    if (bi < 1664) {
        int i = (bi - 512) * 256 + tid;
        wbf[i] = f2bf(conv_w[i]);
        return;
    }
    if (bi < 4736) {
        int i = (bi - 1664) * 256 + tid;
        float4 a = *(const float4*)(x + (size_t)i * 8);
        float4 b = *(const float4*)(x + (size_t)i * 8 + 4);
        short8 o = {f2bf(a.x), f2bf(a.y), f2bf(a.z), f2bf(a.w),
                    f2bf(b.x), f2bf(b.y), f2bf(b.z), f2bf(b.w)};
        *(short8*)(xbf + (size_t)i * 8) = o;
        return;
    }
    if (bi < 4740) {
        int idx = (bi - 4736) * 256 + tid;
        if (idx < 1024) {
            int t = idx >> 5, j = idx & 31;
            float ang = (float)t * expf(-(float)j * (logf(10000.f) / 32.f));
            ropeS[idx] = sinf(ang);
            ropeC[idx] = cosf(ang);
        }
        return;
    }
    __shared__ float tile[32][33];
    int rel0 = bi - 4740;
    const float* src; short* dst; int NT, K, N, rel;
    if (rel0 < 4608)       { src = kqv_w;  dst = kqvT;  NT = 48; K = 512;  N = 1536; rel = rel0; }
    else if (rel0 < 6144)  { src = proj_w; dst = projT; NT = 16; K = 512;  N = 512;  rel = rel0 - 4608; }
    else if (rel0 < 12288) { src = mlp_w1; dst = mlp1T; NT = 64; K = 512;  N = 2048; rel = rel0 - 6144; }
    else                   { src = mlp_w2; dst = mlp2T; NT = 16; K = 2048; N = 512;  rel = rel0 - 12288; }
    int per = NT * (K / 32);
    int layer = rel / per, r2 = rel - layer * per;
    int nt = r2 % NT, kt = r2 / NT;
    src += (size_t)layer * K * N;
    dst += (size_t)layer * N * K;
    int n0 = nt * 32, k0 = kt * 32;
    int lx = tid & 31, ly = tid >> 5;
    #pragma unroll
    for (int i = 0; i < 32; i += 8)
        tile[ly + i][lx] = src[(size_t)(k0 + ly + i) * N + n0 + lx];
    __syncthreads();
    if (tid < 128) {
        int row = tid >> 2, c = tid & 3;
        short8 o;
        #pragma unroll
        for (int j = 0; j < 8; j++) o[j] = f2bf(tile[c * 8 + j][row]);
        *(short8*)(dst + (size_t)(n0 + row) * K + k0 + c * 8) = o;
    }
}

// ---------------------------------------------------------------------------
// conv_fused: unchanged.
__global__ __launch_bounds__(256, 2) void conv_fused(
    const short* __restrict__ xbf, const short* __restrict__ wbf,
    const float* __restrict__ cb, const float* __restrict__ tg,
    const float* __restrict__ tb, const float* __restrict__ gb,
    float* __restrict__ h) {
    __shared__ short As[64 * 32];
    __shared__ short Bs[512 * 32];
    __shared__ float redsum[4][64], redss[4][64];
    __shared__ float mu_s[64], inv_s[64];
    int bt = blockIdx.x, b = bt >> 5, t = bt & 31;
    int tid = threadIdx.x;
    int wave = tid >> 6, lane = tid & 63, quad = lane >> 4, l16 = lane & 15;

    int rowA = tid >> 2;
    int cA = (tid & 3) ^ ((rowA >> 1) & 3);
    int hn = rowA >> 3, wn2 = rowA & 7;
    long long baseA = (((long long)(b * 32 + t - 2) * 3) << 12)
                      + (long long)(hn * 8) * 64 + wn2 * 8;

    f32x4 acc[4][8];
    #pragma unroll
    for (int mt = 0; mt < 4; mt++)
        #pragma unroll
        for (int nt = 0; nt < 8; nt++) acc[mt][nt] = (f32x4){0.f, 0.f, 0.f, 0.f};

    for (int k0 = 0; k0 < 576; k0 += 32) {
        #pragma unroll
        for (int e = 0; e < 8; e++) {
            int s = e * 256 + tid;
            int n = s >> 2;
            int c = (s & 3) ^ ((n >> 1) & 3);
            async16(wbf + (size_t)n * 576 + k0 + c * 8, Bs + s * 8);
        }
        {
            int ks = (k0 >> 3) + cA;
            int ch = (ks >= 24) + (ks >= 48);
            int r = ks - ch * 24;
            int kt = r >> 3, ph = r & 7;
            short8 v8 = (short8){0, 0, 0, 0, 0, 0, 0, 0};
            if (t + kt >= 2)
                v8 = *(const short8*)(xbf + baseA
                        + ((long long)(kt * 3 + ch) << 12) + ph * 64);
            *(short8*)(As + tid * 8) = v8;
        }
        __syncthreads();
        short8 af[4], bf[8];
        #pragma unroll
        for (int mt = 0; mt < 4; mt++) {
            int row = mt * 16 + l16;
            int pc = quad ^ ((row >> 1) & 3);
            af[mt] = *(const short8*)(As + row * 32 + pc * 8);
        }
        #pragma unroll
        for (int nt = 0; nt < 8; nt++) {
            int row = wave * 128 + nt * 16 + l16;
            int pc = quad ^ ((row >> 1) & 3);
            bf[nt] = *(const short8*)(Bs + row * 32 + pc * 8);
        }
        #pragma unroll
        for (int mt = 0; mt < 4; mt++)
            #pragma unroll
            for (int nt = 0; nt < 8; nt++)
                acc[mt][nt] = __builtin_amdgcn_mfma_f32_16x16x32_bf16(
                    af[mt], bf[nt], acc[mt][nt], 0, 0, 0);
        __syncthreads();
    }

    float cbn[8], tgn[8], tbn[8], Gn[8], Ben[8];
    #pragma unroll
    for (int nt = 0; nt < 8; nt++) {
        int n = wave * 128 + nt * 16 + l16;
        cbn[nt] = cb[n]; tgn[nt] = tg[n]; tbn[nt] = tb[n];
        Gn[nt]  = 1.f + 0.5f * gb[bt * 1024 + n];
        Ben[nt] = 0.5f * gb[bt * 1024 + 512 + n];
    }
    #pragma unroll
    for (int mt = 0; mt < 4; mt++)
        #pragma unroll
        for (int reg = 0; reg < 4; reg++) {
            float s = 0.f, ss = 0.f;
            #pragma unroll
            for (int nt = 0; nt < 8; nt++) {
                float v = acc[mt][nt][reg] + cbn[nt];
                s += v; ss += v * v;
            }
            #pragma unroll
            for (int o = 1; o < 16; o <<= 1) {
                s  += __shfl_xor(s, o, 64);
                ss += __shfl_xor(ss, o, 64);
            }
            if (l16 == 0) {
                int m = mt * 16 + quad * 4 + reg;
                redsum[wave][m] = s; redss[wave][m] = ss;
            }
        }
    __syncthreads();
    if (tid < 64) {
        float S  = redsum[0][tid] + redsum[1][tid] + redsum[2][tid] + redsum[3][tid];
        float SS = redss[0][tid] + redss[1][tid] + redss[2][tid] + redss[3][tid];
        float mu = S * (1.f / 512.f);
        float var = SS * (1.f / 512.f) - mu * mu;
        mu_s[tid] = mu; inv_s[tid] = rsqrtf(var + EPS);
    }
    __syncthreads();
    float hacc[8] = {0.f, 0.f, 0.f, 0.f, 0.f, 0.f, 0.f, 0.f};
    #pragma unroll
    for (int mt = 0; mt < 4; mt++)
        #pragma unroll
        for (int reg = 0; reg < 4; reg++) {
            int m = mt * 16 + quad * 4 + reg;
            float mu = mu_s[m], inv = inv_s[m];
            #pragma unroll
            for (int nt = 0; nt < 8; nt++) {
                float v = acc[mt][nt][reg] + cbn[nt];
                hacc[nt] += (v - mu) * inv;
            }
        }
    #pragma unroll
    for (int nt = 0; nt < 8; nt++) {
        hacc[nt] += __shfl_xor(hacc[nt], 16, 64);
        hacc[nt] += __shfl_xor(hacc[nt], 32, 64);
    }
    if (quad == 0)
        #pragma unroll
        for (int nt = 0; nt < 8; nt++) {
            int n = wave * 128 + nt * 16 + l16;
            h[bt * 512 + n] = Gn[nt] * (tgn[nt] * (hacc[nt] * (1.f / 64.f)) + tbn[nt])
                              + Ben[nt];
        }
}

// ---------------------------------------------------------------------------
// P1: attn for one (batch g, head hh). Unchanged from round 4.
// ---------------------------------------------------------------------------
__device__ __forceinline__ void attn_phase(
    char* smem, int g, int hh, int tid,
    const float* __restrict__ hsrc, const float* __restrict__ lng,
    const float* __restrict__ lnb, const short* __restrict__ Bw,
    const float* __restrict__ bias, const float* __restrict__ ropeS,
    const float* __restrict__ ropeC, short* __restrict__ yv) {
    float* mu_s = (float*)(smem + 65536);
    float* inv_s = (float*)(smem + 65664);
    short* As = (short*)smem;                      // 32 KB
    short* BsB[2] = {(short*)(smem + 32768), (short*)(smem + 45056)};  // 12 KB ea
    float (*qsf)[64] = (float(*)[64])(smem);
    float (*ksf)[64] = (float(*)[64])(smem + 8192);
    short* vT  = (short*)(smem + 16384);
    short* qrb = (short*)(smem + 20480);
    short* krb = (short*)(smem + 24576);
    float (*att)[33] = (float(*)[33])(smem + 28672);
    short* pA  = (short*)(smem + 36864);
    short* yv_s = (short*)(smem + 28672);          // 32x64 bf16 (after softmax)
    int m0 = g * 32;
    // early prefetch of B k0=0 (overlaps LN pass 1)
    #pragma unroll
    for (int e = 0; e < 3; e++) {
        int p = e * 256 + tid;
        int row = p >> 2, seg = (p & 3) ^ ((row >> 1) & 3);
        int n = ((row >> 6) << 9) + hh * 64 + (row & 63);
        async16(Bw + (size_t)n * 512 + seg * 8, BsB[0] + p * 8);
    }
    // LN pass 1 (sc1)
    {
        int row = tid >> 3, l8 = tid & 7;
        const float* hp = hsrc + (size_t)(m0 + row) * 512 + l8 * 64;
        float s = 0.f, ss = 0.f;
        #pragma unroll
        for (int i = 0; i < 32; i++) {
            float2 v = ald2(hp + i * 2);
            s += v.x + v.y;
            ss += v.x * v.x + v.y * v.y;
        }
        s += __shfl_xor(s, 1, 64); ss += __shfl_xor(ss, 1, 64);
        s += __shfl_xor(s, 2, 64); ss += __shfl_xor(ss, 2, 64);
        s += __shfl_xor(s, 4, 64); ss += __shfl_xor(ss, 4, 64);
        if (l8 == 0) {
            float mu = s * (1.f / 512.f);
            float var = ss * (1.f / 512.f) - mu * mu;
            mu_s[row] = mu;
            inv_s[row] = rsqrtf(var + EPS);
        }
    }
    __syncthreads();
    // LN pass 2 -> As (sc1)
    #pragma unroll
    for (int e = 0; e < 8; e++) {
        int lc = e * 256 + tid;
        int row = lc >> 6, cc = lc & 63;
        float mu = mu_s[row], inv = inv_s[row];
        const float* hp = hsrc + (size_t)(m0 + row) * 512 + cc * 8;
        float2 p0 = ald2(hp), p1 = ald2(hp + 2), p2 = ald2(hp + 4), p3 = ald2(hp + 6);
        float4 g0 = *(const float4*)(lng + cc * 8), g1 = *(const float4*)(lng + cc * 8 + 4);
        float4 b0 = *(const float4*)(lnb + cc * 8), b1 = *(const float4*)(lnb + cc * 8 + 4);
        short8 o = {f2bf((p0.x - mu) * inv * g0.x + b0.x),
                    f2bf((p0.y - mu) * inv * g0.y + b0.y),
                    f2bf((p1.x - mu) * inv * g0.z + b0.z),
                    f2bf((p1.y - mu) * inv * g0.w + b0.w),
                    f2bf((p2.x - mu) * inv * g1.x + b1.x),
                    f2bf((p2.y - mu) * inv * g1.y + b1.y),
                    f2bf((p3.x - mu) * inv * g1.z + b1.z),
                    f2bf((p3.y - mu) * inv * g1.w + b1.w)};
        *(short8*)(As + (row * 64 + (cc ^ (row & 7))) * 8) = o;
    }
    __syncthreads();
    int wave = tid >> 6, lane = tid & 63, quad = lane >> 4, l16 = lane & 15;
    f32x4 acc[2][3];
    #pragma unroll
    for (int m2 = 0; m2 < 2; m2++)
        #pragma unroll
        for (int gg = 0; gg < 3; gg++) acc[m2][gg] = (f32x4){0.f, 0.f, 0.f, 0.f};
    for (int it = 0; it < 16; it++) {
        short* Bsc = BsB[it & 1];
        if (it < 15) {
            int k0n = (it + 1) * 32;
            short* Bsn = BsB[(it + 1) & 1];
            #pragma unroll
            for (int e = 0; e < 3; e++) {
                int p = e * 256 + tid;
                int row = p >> 2, seg = (p & 3) ^ ((row >> 1) & 3);
                int n = ((row >> 6) << 9) + hh * 64 + (row & 63);
                async16(Bw + (size_t)n * 512 + k0n + seg * 8, Bsn + p * 8);
            }
        }
        int cc = it * 4 + quad;
        short8 af[2], bf[3];
        #pragma unroll
        for (int m2 = 0; m2 < 2; m2++) {
            int row = m2 * 16 + l16;
            af[m2] = *(const short8*)(As + (row * 64 + (cc ^ (row & 7))) * 8);
        }
        #pragma unroll
        for (int gg = 0; gg < 3; gg++) {
            int row = gg * 64 + wave * 16 + l16;
            int pc = quad ^ ((row >> 1) & 3);
            bf[gg] = *(const short8*)(Bsc + (row * 4 + pc) * 8);
        }
        #pragma unroll
        for (int m2 = 0; m2 < 2; m2++)
            #pragma unroll
            for (int gg = 0; gg < 3; gg++)
                acc[m2][gg] = __builtin_amdgcn_mfma_f32_16x16x32_bf16(
                    af[m2], bf[gg], acc[m2][gg], 0, 0, 0);
        __syncthreads();
    }
    // epilogue: k,q fp32 -> LDS; v -> vT bf16
    float bb0 = bias[hh * 64 + wave * 16 + l16];
    float bb1 = bias[512 + hh * 64 + wave * 16 + l16];
    float bb2 = bias[1024 + hh * 64 + wave * 16 + l16];
    int dcol = wave * 16 + l16;
    #pragma unroll
    for (int m2 = 0; m2 < 2; m2++)
        #pragma unroll
        for (int reg = 0; reg < 4; reg++) {
            int tkn = m2 * 16 + quad * 4 + reg;
            ksf[tkn][dcol] = acc[m2][0][reg] + bb0;
            qsf[tkn][dcol] = acc[m2][1][reg] + bb1;
            vT[dcol * 32 + (((tkn >> 3) ^ (dcol & 3)) << 3) + (tkn & 7)]
                = f2bf(acc[m2][2][reg] + bb2);
        }
    __syncthreads();
    // RoPE (table)
    #pragma unroll
    for (int e = 0; e < 8; e++) {
        int idx = e * 256 + tid;
        int t = idx >> 6, d = idx & 63, j = d & 31;
        float sv = ropeS[t * 32 + j], cv = ropeC[t * 32 + j];
        float qv = qsf[t][d], kv = ksf[t][d];
        float qo = qsf[t][d ^ 32], ko = ksf[t][d ^ 32];
        float rq = (d < 32) ? -qo : qo;
        float rk = (d < 32) ? -ko : ko;
        int addr = t * 64 + (((d >> 3) ^ (t & 7)) << 3) + (d & 7);
        qrb[addr] = f2bf(qv * cv + rq * sv);
        krb[addr] = f2bf(kv * cv + rk * sv);
    }
    __syncthreads();
    int mw = wave & 1, nw = wave >> 1;
    // QK^T via MFMA
    {
        f32x4 sc = (f32x4){0.f, 0.f, 0.f, 0.f};
        #pragma unroll
        for (int kc = 0; kc < 2; kc++) {
            int rq = mw * 16 + l16;
            int rk = nw * 16 + l16;
            short8 aq = *(const short8*)(qrb + rq * 64 + ((((kc << 2) + quad) ^ (rq & 7)) << 3));
            short8 bk = *(const short8*)(krb + rk * 64 + ((((kc << 2) + quad) ^ (rk & 7)) << 3));
            sc = __builtin_amdgcn_mfma_f32_16x16x32_bf16(aq, bk, sc, 0, 0, 0);
        }
        #pragma unroll
        for (int reg = 0; reg < 4; reg++) {
            int qt = mw * 16 + quad * 4 + reg;
            int kt = nw * 16 + l16;
            att[qt][kt] = (kt > qt) ? -1e30f : sc[reg] * 0.125f;
        }
    }
    __syncthreads();
    // softmax
    {
        int row = tid >> 3, gg = tid & 7;
        float v0 = att[row][gg * 4], v1 = att[row][gg * 4 + 1];
        float v2 = att[row][gg * 4 + 2], v3 = att[row][gg * 4 + 3];
        float mx = fmaxf(fmaxf(v0, v1), fmaxf(v2, v3));
        mx = fmaxf(mx, __shfl_xor(mx, 1, 64));
        mx = fmaxf(mx, __shfl_xor(mx, 2, 64));
        mx = fmaxf(mx, __shfl_xor(mx, 4, 64));
        float e0 = expf(v0 - mx), e1 = expf(v1 - mx);
        float e2 = expf(v2 - mx), e3 = expf(v3 - mx);
        float s = e0 + e1 + e2 + e3;
        s += __shfl_xor(s, 1, 64);
        s += __shfl_xor(s, 2, 64);
        s += __shfl_xor(s, 4, 64);
        float inv = 1.f / s;
        short* pp = pA + row * 32 + gg * 4;
        pp[0] = f2bf(e0 * inv); pp[1] = f2bf(e1 * inv);
        pp[2] = f2bf(e2 * inv); pp[3] = f2bf(e3 * inv);
    }
    __syncthreads();
    // PV via MFMA -> stage to LDS
    {
        int rp = mw * 16 + l16;
        short8 ap = *(const short8*)(pA + rp * 32 + quad * 8);
        #pragma unroll
        for (int i = 0; i < 2; i++) {
            int nt = (wave >> 1) * 2 + i;
            int rv = nt * 16 + l16;
            short8 bv = *(const short8*)(vT + rv * 32 + (((quad ^ (rv & 3))) << 3));
            f32x4 o = (f32x4){0.f, 0.f, 0.f, 0.f};
            o = __builtin_amdgcn_mfma_f32_16x16x32_bf16(ap, bv, o, 0, 0, 0);
            #pragma unroll
            for (int reg = 0; reg < 4; reg++) {
                int t = mw * 16 + quad * 4 + reg;
                int d = nt * 16 + l16;
                yv_s[t * 64 + d] = f2bf(o[reg]);
            }
        }
    }
    __syncthreads();
    // cooperative sc1 store of the 32x64 slice
    #pragma unroll
    for (int e = 0; e < 2; e++) {
        int idx = e * 256 + tid;
        int t = idx >> 4, c = idx & 15;
        astu(yv + (size_t)(m0 + t) * 512 + hh * 64 + c * 4,
             *(const unsigned long long*)(yv_s + t * 64 + c * 4));
    }
}

// ---------------------------------------------------------------------------
// P2: proj + gated residual (16 active WGs/group, 32-col slices). Unchanged.
// ---------------------------------------------------------------------------
__device__ __forceinline__ void proj_phase(
    char* smem, int g, int wgl, int tid,
    const float* __restrict__ hA, const short* __restrict__ yv,
    const short* __restrict__ Bw, const float* __restrict__ bias,
    const float* __restrict__ rsPtr, float* __restrict__ hB) {
    short* As = (short*)smem;               // 32KB
    short* Bs = (short*)(smem + 32768);     // 32KB
    int m0 = g * 32, n0 = wgl * 32;
    #pragma unroll
    for (int e = 0; e < 8; e++) {
        int p = e * 256 + tid;
        int row = p >> 6, c = p & 63;
        int cl = c ^ (row & 7);
        async16(Bw + (size_t)(n0 + row) * 512 + cl * 8, Bs + p * 8);
    }
    #pragma unroll
    for (int e = 0; e < 8; e++) {
        int p = e * 256 + tid;
        int row = p >> 6, c = p & 63;
        const short* src = yv + (size_t)(m0 + row) * 512 + c * 8;
        unsigned long long a = aldu(src), b = aldu(src + 4);
        short* d = As + (row * 64 + (c ^ (row & 7))) * 8;
        *(unsigned long long*)d = a;
        *(unsigned long long*)(d + 4) = b;
    }
    __syncthreads();
    int wave = tid >> 6, lane = tid & 63, quad = lane >> 4, l16 = lane & 15;
    int mw = wave & 1, nw = wave >> 1;
    f32x4 acc = (f32x4){0.f, 0.f, 0.f, 0.f};
    #pragma unroll
    for (int kk = 0; kk < 16; kk++) {
        int cc = kk * 4 + quad;
        int ra = mw * 16 + l16, rb = nw * 16 + l16;
        short8 af = *(const short8*)(As + (ra * 64 + (cc ^ (ra & 7))) * 8);
        short8 bf = *(const short8*)(Bs + (rb * 64 + (cc ^ (rb & 7))) * 8);
        acc = __builtin_amdgcn_mfma_f32_16x16x32_bf16(af, bf, acc, 0, 0, 0);
    }
    float rsv = *rsPtr;
    #pragma unroll
    for (int reg = 0; reg < 4; reg++) {
        int m = m0 + mw * 16 + quad * 4 + reg;
        int n = n0 + nw * 16 + l16;
        float base = ald1(hA + (size_t)m * 512 + n);
        float v = base + rsv * (acc[reg] + bias[n]);
        ast1(hB + (size_t)m * 512 + n, v);
    }
}

// ---------------------------------------------------------------------------
// P3: LN2 + mlp1 + GELU -> mb (32 active WGs/group, 64-col slices). Also
// zeroes this group's hA slice (P4's atomicAdd target).
// ---------------------------------------------------------------------------
__device__ __forceinline__ void mlp1_phase(
    char* smem, int g, int wgl, int tid,
    const float* __restrict__ hB, const float* __restrict__ lng,
    const float* __restrict__ lnb, const short* __restrict__ Bw,
    const float* __restrict__ bias, short* __restrict__ mb,
    float* __restrict__ hA) {
    short* As = (short*)smem;                // 32KB
    short* Bs = (short*)(smem + 32768);      // 16KB (64 rows x 128k)
    float* mu_s = (float*)(smem + 65536);
    float* inv_s = (float*)(smem + 65664);
    int m0 = g * 32, n0 = wgl * 64;
    // B prefetch k0=0 (hoisted to top)
    #pragma unroll
    for (int e = 0; e < 4; e++) {
        int p = e * 256 + tid;
        int row = p >> 4, seg = (p & 15) ^ (row & 15);
        async16(Bw + (size_t)(n0 + row) * 512 + seg * 8, Bs + p * 8);
    }
    // zero hA slice (32 WGs x 512 floats)
    {
        float* za = hA + (size_t)m0 * 512 + wgl * 512 + tid * 2;
        astu(za, 0ull);
    }
    // LN pass1 (sc1)
    {
        int row = tid >> 3, l8 = tid & 7;
        const float* hp = hB + (size_t)(m0 + row) * 512 + l8 * 64;
        float s = 0.f, ss = 0.f;
        #pragma unroll
        for (int i = 0; i < 32; i++) {
            float2 v = ald2(hp + i * 2);
            s += v.x + v.y;
            ss += v.x * v.x + v.y * v.y;
        }
        s += __shfl_xor(s, 1, 64); ss += __shfl_xor(ss, 1, 64);
        s += __shfl_xor(s, 2, 64); ss += __shfl_xor(ss, 2, 64);
        s += __shfl_xor(s, 4, 64); ss += __shfl_xor(ss, 4, 64);
        if (l8 == 0) {
            float mu = s * (1.f / 512.f);
            float var = ss * (1.f / 512.f) - mu * mu;
            mu_s[row] = mu;
            inv_s[row] = rsqrtf(var + EPS);
        }
    }
    __syncthreads();
    // LN pass2 -> As (sc1)
    #pragma unroll
    for (int e = 0; e < 8; e++) {
        int lc = e * 256 + tid;
        int row = lc >> 6, cc = lc & 63;
        float mu = mu_s[row], inv = inv_s[row];
        const float* hp = hB + (size_t)(m0 + row) * 512 + cc * 8;
        float2 p0 = ald2(hp), p1 = ald2(hp + 2), p2 = ald2(hp + 4), p3 = ald2(hp + 6);
        float4 g0 = *(const float4*)(lng + cc * 8), g1 = *(const float4*)(lng + cc * 8 + 4);
        float4 b0 = *(const float4*)(lnb + cc * 8), b1 = *(const float4*)(lnb + cc * 8 + 4);
        short8 o = {f2bf((p0.x - mu) * inv * g0.x + b0.x),
                    f2bf((p0.y - mu) * inv * g0.y + b0.y),
                    f2bf((p1.x - mu) * inv * g0.z + b0.z),
                    f2bf((p1.y - mu) * inv * g0.w + b0.w),
                    f2bf((p2.x - mu) * inv * g1.x + b1.x),
                    f2bf((p2.y - mu) * inv * g1.y + b1.y),
                    f2bf((p3.x - mu) * inv * g1.z + b1.z),
                    f2bf((p3.y - mu) * inv * g1.w + b1.w)};
        *(short8*)(As + (row * 64 + (cc ^ (row & 7))) * 8) = o;
    }
    __syncthreads();
    int wave = tid >> 6, lane = tid & 63, quad = lane >> 4, l16 = lane & 15;
    f32x4 acc[2];
    acc[0] = (f32x4){0.f, 0.f, 0.f, 0.f};
    acc[1] = (f32x4){0.f, 0.f, 0.f, 0.f};
    for (int it = 0; it < 4; it++) {
        int k0 = it * 128;
        #pragma unroll
        for (int ksub = 0; ksub < 4; ksub++) {
            int ccb = ksub * 4 + quad;
            int rowb = wave * 16 + l16;
            short8 bf = *(const short8*)(Bs + (rowb * 16 + (ccb ^ (rowb & 15))) * 8);
            #pragma unroll
            for (int m2 = 0; m2 < 2; m2++) {
                int row = m2 * 16 + l16;
                int cc = (k0 >> 3) + ccb;
                short8 af = *(const short8*)(As + (row * 64 + (cc ^ (row & 7))) * 8);
                acc[m2] = __builtin_amdgcn_mfma_f32_16x16x32_bf16(af, bf, acc[m2], 0, 0, 0);
            }
        }
        __syncthreads();
        if (it < 3) {
            int k0n = (it + 1) * 128;
            #pragma unroll
            for (int e = 0; e < 4; e++) {
                int p = e * 256 + tid;
                int row = p >> 4, seg = (p & 15) ^ (row & 15);
                async16(Bw + (size_t)(n0 + row) * 512 + k0n + seg * 8, Bs + p * 8);
            }
            __syncthreads();
        }
    }
    __syncthreads();
    // GELU -> stage into As region (dead) -> sc1 bulk store
    short* outS = As;   // 32x64 bf16 = 4KB
    #pragma unroll
    for (int m2 = 0; m2 < 2; m2++)
        #pragma unroll
        for (int reg = 0; reg < 4; reg++) {
            int mr = m2 * 16 + quad * 4 + reg;
            int nr = wave * 16 + l16;
            float v = acc[m2][reg] + bias[n0 + nr];
            v = 0.5f * v * (1.f + erff(v * 0.70710678118f));
            outS[mr * 64 + nr] = f2bf(v);
        }
    __syncthreads();
    #pragma unroll
    for (int e = 0; e < 2; e++) {
        int idx = e * 256 + tid;
        int m = idx >> 4, c = idx & 15;
        astu(mb + (size_t)(m0 + m) * 2048 + n0 + c * 4,
             *(const unsigned long long*)(outS + m * 64 + c * 4));
    }
}

// ---------------------------------------------------------------------------
// P4: mlp2 + gated residual into zeroed hA via atomicAdd. 32 WGs/group =
// 8 n-slices (64 cols) x 4 K-quarters (Ks=512). BK=128, double-buffered.
// ---------------------------------------------------------------------------
__device__ __forceinline__ void mlp2_phase(
    char* smem, int g, int wgl, int tid,
    const float* __restrict__ hB, const short* __restrict__ mb,
    const short* __restrict__ Bw, const float* __restrict__ bias,
    const float* __restrict__ rsPtr, float* __restrict__ hA) {
    short* As = (short*)smem;               // 2 x 8KB
    short* Bs = (short*)(smem + 16384);     // 2 x 16KB
    int kz = wgl & 3, nb = wgl >> 2;
    int m0 = g * 32, n0 = nb * 64, kbase = kz * 512;
    int wave = tid >> 6, lane = tid & 63, quad = lane >> 4, l16 = lane & 15;
    f32x4 acc[2];
    acc[0] = (f32x4){0.f, 0.f, 0.f, 0.f};
    acc[1] = (f32x4){0.f, 0.f, 0.f, 0.f};
    unsigned long long r0, r1, r2, r3;
    int rowA0 = tid >> 4, segA0 = (tid & 15) ^ (rowA0 & 15);
    int rowA1 = (256 + tid) >> 4, segA1 = ((256 + tid) & 15) ^ (rowA1 & 15);
    auto ldA = [&](int k0) {
        const short* s0 = mb + (size_t)(m0 + rowA0) * 2048 + k0 + segA0 * 8;
        const short* s1 = mb + (size_t)(m0 + rowA1) * 2048 + k0 + segA1 * 8;
        r0 = aldu(s0); r1 = aldu(s0 + 4);
        r2 = aldu(s1); r3 = aldu(s1 + 4);
    };
    auto wrA = [&](int buf) {
        *(unsigned long long*)(As + buf * 4096 + tid * 8) = r0;
        *(unsigned long long*)(As + buf * 4096 + tid * 8 + 4) = r1;
        *(unsigned long long*)(As + buf * 4096 + (256 + tid) * 8) = r2;
        *(unsigned long long*)(As + buf * 4096 + (256 + tid) * 8 + 4) = r3;
    };
    auto stB = [&](int k0, int buf) {
        #pragma unroll
        for (int e = 0; e < 4; e++) {
            int p = e * 256 + tid;
            int row = p >> 4, seg = (p & 15) ^ (row & 15);
            async16(Bw + (size_t)(n0 + row) * 2048 + k0 + seg * 8,
                    Bs + buf * 8192 + p * 8);
        }
    };
    ldA(kbase); stB(kbase, 0); wrA(0);
    __syncthreads();
    for (int it = 0; it < 4; it++) {
        int cur = it & 1;
        if (it < 3) { stB(kbase + (it + 1) * 128, cur ^ 1); ldA(kbase + (it + 1) * 128); }
        #pragma unroll
        for (int ksub = 0; ksub < 4; ksub++) {
            int ccb = ksub * 4 + quad;
            int rb = wave * 16 + l16;
            short8 bf = *(const short8*)(Bs + cur * 8192 + (rb * 16 + (ccb ^ (rb & 15))) * 8);
            #pragma unroll
            for (int m2 = 0; m2 < 2; m2++) {
                int ra = m2 * 16 + l16;
                short8 af = *(const short8*)(As + cur * 4096 + (ra * 16 + (ccb ^ (ra & 15))) * 8);
                acc[m2] = __builtin_amdgcn_mfma_f32_16x16x32_bf16(af, bf, acc[m2], 0, 0, 0);
            }
        }
        if (it < 3) wrA(cur ^ 1);
        __syncthreads();
    }
    float rsv = *rsPtr;
    #pragma unroll
    for (int m2 = 0; m2 < 2; m2++)
        #pragma unroll
        for (int reg = 0; reg < 4; reg++) {
            int m = m0 + m2 * 16 + quad * 4 + reg;
            int n = n0 + wave * 16 + l16;
            float v = rsv * (acc[m2][reg] + (kz == 0 ? bias[n] : 0.f));
            if (kz == 0) v += ald1(hB + (size_t)m * 512 + n);
            atomicAdd(&hA[(size_t)m * 512 + n], v);
        }
}

// ---------------------------------------------------------------------------
__device__ __forceinline__ void head_phase(
    char* smem, int token, int tid,
    const float* __restrict__ h, const float* __restrict__ g,
    const float* __restrict__ bb, const float* __restrict__ w,
    const float* __restrict__ bias0, float* __restrict__ out) {
    float* red = (float*)smem;
    float v0 = ald1(h + (size_t)token * 512 + tid);
    float v1 = ald1(h + (size_t)token * 512 + tid + 256);
    float s  = block_reduce_sum_256(v0 + v1, red);
    float ss = block_reduce_sum_256(v0 * v0 + v1 * v1, red);
    float mu = s * (1.f / 512.f);
    float var = ss * (1.f / 512.f) - mu * mu;
    float inv = rsqrtf(var + EPS);
    float n0 = (v0 - mu) * inv * g[tid] + bb[tid];
    float n1 = (v1 - mu) * inv * g[tid + 256] + bb[tid + 256];
    float dot = block_reduce_sum_256(n0 * w[tid] + n1 * w[tid + 256], red);
    if (tid == 0) out[token] = dot + bias0[0];
}

// ---------------------------------------------------------------------------
// mega v4: identical structure to v3 (16 groups x 32 WGs = 512 WGs) but NO
// min-occupancy launch hint: the R4 (256,2) hint forced VGPRs 248->128 and
// spilled to scratch (WRITE_SIZE 46->157MB). At the natural ~248 VGPRs,
// 2 waves/SIMD fit anyway -> 2 blocks/CU co-residency without spills.
// Groups are contiguous 32-WG spans, so even 1-block/CU residency executes
// whole groups sequentially (no deadlock).
// ---------------------------------------------------------------------------
__global__ __launch_bounds__(256) void mega(
    float* __restrict__ hA, float* __restrict__ hB,
    short* __restrict__ yvb, short* __restrict__ mbuf,
    const float* __restrict__ ropeS, const float* __restrict__ ropeC,
    const short* __restrict__ kqvT, const short* __restrict__ projT,
    const short* __restrict__ mlp1T, const short* __restrict__ mlp2T,
    const float* __restrict__ ln1_g, const float* __restrict__ ln1_b,
    const float* __restrict__ kqv_b, const float* __restrict__ proj_b,
    const float* __restrict__ ln2_g, const float* __restrict__ ln2_b,
    const float* __restrict__ mlp_b1, const float* __restrict__ mlp_b2,
    const float* __restrict__ rs_attn, const float* __restrict__ rs_mlp,
    const float* __restrict__ head_g, const float* __restrict__ head_b,
    const float* __restrict__ head_w, const float* __restrict__ head_bs,
    float* __restrict__ out, unsigned* __restrict__ bar) {
    __shared__ char smem[65792] __attribute__((aligned(16)));
    int wg = blockIdx.x, tid = threadIdx.x;
    int g = wg >> 5, wgl = wg & 31;
    unsigned* flag = bar + g * 32;   // 128B spacing
    unsigned goal = 0;

    for (int i = 0; i < 6; i++) {
        // ---- P1: attn (8 head-WGs per group) ----
        if (wgl < 8)
            attn_phase(smem, g, wgl, tid, hA, ln1_g + i * 512, ln1_b + i * 512,
                       kqvT + (size_t)i * 786432, kqv_b + i * 1536,
                       ropeS, ropeC, yvb);
        goal += 32; group_sync(flag, goal);
        // ---- P2: proj + residual -> hB (16 WGs x 32-col slices) ----
        if (wgl < 16)
            proj_phase(smem, g, wgl, tid, hA, yvb,
                       projT + (size_t)i * 262144, proj_b + i * 512,
                       rs_attn + i, hB);
        goal += 32; group_sync(flag, goal);
        // ---- P3: LN2 + mlp1 + GELU -> mbuf (32 WGs x 64-col; zeroes hA) ----
        mlp1_phase(smem, g, wgl, tid, hB, ln2_g + i * 512, ln2_b + i * 512,
                   mlp1T + (size_t)i * 1048576, mlp_b1 + i * 2048, mbuf, hA);
        goal += 32; group_sync(flag, goal);
        // ---- P4: mlp2 + residual -> hA (32 WGs = 8n x 4kz, atomicAdd) ----
        mlp2_phase(smem, g, wgl, tid, hB, mbuf,
                   mlp2T + (size_t)i * 1048576, mlp_b2 + i * 512,
                   rs_mlp + i, hA);
        goal += 32; group_sync(flag, goal);
    }
    // ---- head: 1 token per WG (512 tokens) ----
    head_phase(smem, wg, tid, hA, head_g, head_b, head_w, head_bs, out);
}

// ---------------------------------------------------------------------------
extern "C" void kernel_launch(void* const* d_in, const int* in_sizes, int n_in,
                              void* d_out, int out_size, void* d_ws, size_t ws_size,
                              hipStream_t stream) {
    const float* x       = (const float*)d_in[0];
    const float* z       = (const float*)d_in[1];
    const float* conv_w  = (const float*)d_in[2];
    const float* conv_b  = (const float*)d_in[3];
    const float* tok_g   = (const float*)d_in[4];
    const float* tok_b   = (const float*)d_in[5];
    const float* film_w  = (const float*)d_in[6];
    const float* film_b  = (const float*)d_in[7];
    const float* ln1_g   = (const float*)d_in[8];
    const float* ln1_b   = (const float*)d_in[9];
    const float* kqv_w   = (const float*)d_in[10];
    const float* kqv_b   = (const float*)d_in[11];
    const float* proj_w  = (const float*)d_in[12];
    const float* proj_b  = (const float*)d_in[13];
    const float* ln2_g   = (const float*)d_in[14];
    const float* ln2_b   = (const float*)d_in[15];
    const float* mlp_w1  = (const float*)d_in[16];
    const float* mlp_b1  = (const float*)d_in[17];
    const float* mlp_w2  = (const float*)d_in[18];
    const float* mlp_b2  = (const float*)d_in[19];
    const float* rs_attn = (const float*)d_in[20];
    const float* rs_mlp  = (const float*)d_in[21];
    const float* head_g  = (const float*)d_in[22];
    const float* head_b  = (const float*)d_in[23];
    const float* head_w  = (const float*)d_in[24];
    const float* head_bs = (const float*)d_in[25];
    float* out = (float*)d_out;

    float* ws = (float*)d_ws;
    float* gb    = ws;                  // 524288 f  (FiLM; dead after conv -> hB)
    float* h     = gb + 524288;         // 262144 f  (hA)
    float* ropeS = h + 262144;          // 1024 f
    float* ropeC = ropeS + 1024;        // 1024 f
    short* sb = (short*)(ropeC + 1024);
    short* wbf   = sb;                 // 294912
    short* kqvT  = wbf   + 294912;     // 4718592
    short* projT = kqvT  + 4718592;    // 1572864
    short* mlp1T = projT + 1572864;    // 6291456
    short* mlp2T = mlp1T + 6291456;    // 6291456
    short* yvb   = mlp2T + 6291456;    // 262144
    short* mbuf  = yvb   + 262144;     // 1048576
    short* xbf   = mbuf  + 1048576;    // 6291456
    unsigned* bar = (unsigned*)(xbf + 6291456);   // 512 u32
    float* hB = gb;                    // reuse (1 MB needed of 2 MB)

    prep_all<<<23172, 256, 0, stream>>>(
        z, film_w, film_b, gb, conv_w, wbf, x, xbf, ropeS, ropeC,
        kqv_w, kqvT, proj_w, projT, mlp_w1, mlp1T, mlp_w2, mlp2T, bar);

    conv_fused<<<512, 256, 0, stream>>>(xbf, wbf, conv_b, tok_g, tok_b, gb, h);

    mega<<<512, 256, 0, stream>>>(
        h, hB, yvb, mbuf, ropeS, ropeC, kqvT, projT, mlp1T, mlp2T,
        ln1_g, ln1_b, kqv_b, proj_b, ln2_g, ln2_b, mlp_b1, mlp_b2,
        rs_attn, rs_mlp, head_g, head_b, head_w, head_bs, out, bar);
}

// Round 6
// 594.869 us; speedup vs baseline: 1.7296x; 1.5109x over previous
//
#include <hip/hip_runtime.h>
#include <math.h>

#define EPS 1e-5f

typedef __attribute__((ext_vector_type(8))) short short8;
typedef __attribute__((ext_vector_type(4))) float f32x4;

__device__ __forceinline__ short f2bf(float f) {
    unsigned u = __float_as_uint(f);
    u += 0x7fffu + ((u >> 16) & 1u);
    return (short)(u >> 16);
}
__device__ __forceinline__ float bf2f(short s) {
    return __uint_as_float(((unsigned)(unsigned short)s) << 16);
}
__device__ __forceinline__ void async16(const void* g, void* l) {
    __builtin_amdgcn_global_load_lds(
        (const __attribute__((address_space(1))) unsigned*)g,
        (__attribute__((address_space(3))) unsigned*)l, 16, 0, 0);
}

// ---------------------------------------------------------------------------
// Agent-scope (coherent-point) load/store helpers for cross-WG data.
// ---------------------------------------------------------------------------
__device__ __forceinline__ unsigned long long aldu(const void* p) {
    return __hip_atomic_load((const unsigned long long*)p, __ATOMIC_RELAXED,
                             __HIP_MEMORY_SCOPE_AGENT);
}
__device__ __forceinline__ void astu(void* p, unsigned long long v) {
    __hip_atomic_store((unsigned long long*)p, v, __ATOMIC_RELAXED,
                       __HIP_MEMORY_SCOPE_AGENT);
}
__device__ __forceinline__ float2 ald2(const float* p) {
    unsigned long long u = aldu(p);
    float2 f;
    f.x = __uint_as_float((unsigned)u);
    f.y = __uint_as_float((unsigned)(u >> 32));
    return f;
}
__device__ __forceinline__ float ald1(const float* p) {
    return __uint_as_float(__hip_atomic_load((const unsigned*)p, __ATOMIC_RELAXED,
                                             __HIP_MEMORY_SCOPE_AGENT));
}

// ---------------------------------------------------------------------------
// Per-group barrier (16 WGs). Release fetch_add + relaxed polling.
// ---------------------------------------------------------------------------
__device__ __forceinline__ void group_sync(unsigned* flag, unsigned goal) {
    __syncthreads();
    if (threadIdx.x == 0) {
        __hip_atomic_fetch_add(flag, 1u, __ATOMIC_RELEASE, __HIP_MEMORY_SCOPE_AGENT);
        unsigned spins = 0;
        while (__hip_atomic_load(flag, __ATOMIC_RELAXED, __HIP_MEMORY_SCOPE_AGENT) < goal) {
            __builtin_amdgcn_s_sleep(1);
            if (++spins > 2000000u) break;   // deadlock bailout
        }
    }
    __syncthreads();
}

// ---------------------------------------------------------------------------
__device__ __forceinline__ float block_reduce_sum_256(float v, float* red) {
    #pragma unroll
    for (int o = 32; o > 0; o >>= 1) v += __shfl_down(v, o, 64);
    __syncthreads();
    if ((threadIdx.x & 63) == 0) red[threadIdx.x >> 6] = v;
    __syncthreads();
    return red[0] + red[1] + red[2] + red[3];
}

// ---------------------------------------------------------------------------
// prep_all: + zeroes bar (512 u32) and R1 (262144 f, blocks >= 23172).
__global__ __launch_bounds__(256) void prep_all(
    const float* __restrict__ z, const float* __restrict__ fw,
    const float* __restrict__ fb, float* __restrict__ gb,
    const float* __restrict__ conv_w, short* __restrict__ wbf,
    const float* __restrict__ x, short* __restrict__ xbf,
    float* __restrict__ ropeS, float* __restrict__ ropeC,
    const float* __restrict__ kqv_w, short* __restrict__ kqvT,
    const float* __restrict__ proj_w, short* __restrict__ projT,
    const float* __restrict__ mlp_w1, short* __restrict__ mlp1T,
    const float* __restrict__ mlp_w2, short* __restrict__ mlp2T,
    unsigned* __restrict__ bar, float* __restrict__ zbuf) {
    int bi = blockIdx.x, tid = threadIdx.x;
    if (bi == 0) { bar[tid] = 0u; bar[tid + 256] = 0u; }
    if (bi >= 23172) {
        int idx = (bi - 23172) * 256 + tid;
        float4 z4 = {0.f, 0.f, 0.f, 0.f};
        ((float4*)zbuf)[idx] = z4;
        return;
    }
    if (bi < 512) {
        __shared__ float zs[32];
        if (tid < 32) zs[tid] = z[bi * 32 + tid];
        __syncthreads();
        for (int j = tid; j < 1024; j += 256) {
            float acc = fb[j];
            #pragma unroll
            for (int k = 0; k < 32; k++) acc = fmaf(zs[k], fw[k * 1024 + j], acc);
            gb[bi * 1024 + j] = acc;
        }
        return;
    }
    if (bi < 1664) {
        int i = (bi - 512) * 256 + tid;
        wbf[i] = f2bf(conv_w[i]);
        return;
    }
    if (bi < 4736) {
        int i = (bi - 1664) * 256 + tid;
        float4 a = *(const float4*)(x + (size_t)i * 8);
        float4 b = *(const float4*)(x + (size_t)i * 8 + 4);
        short8 o = {f2bf(a.x), f2bf(a.y), f2bf(a.z), f2bf(a.w),
                    f2bf(b.x), f2bf(b.y), f2bf(b.z), f2bf(b.w)};
        *(short8*)(xbf + (size_t)i * 8) = o;
        return;
    }
    if (bi < 4740) {
        int idx = (bi - 4736) * 256 + tid;
        if (idx < 1024) {
            int t = idx >> 5, j = idx & 31;
            float ang = (float)t * expf(-(float)j * (logf(10000.f) / 32.f));
            ropeS[idx] = sinf(ang);
            ropeC[idx] = cosf(ang);
        }
        return;
    }
    __shared__ float tile[32][33];
    int rel0 = bi - 4740;
    const float* src; short* dst; int NT, K, N, rel;
    if (rel0 < 4608)       { src = kqv_w;  dst = kqvT;  NT = 48; K = 512;  N = 1536; rel = rel0; }
    else if (rel0 < 6144)  { src = proj_w; dst = projT; NT = 16; K = 512;  N = 512;  rel = rel0 - 4608; }
    else if (rel0 < 12288) { src = mlp_w1; dst = mlp1T; NT = 64; K = 512;  N = 2048; rel = rel0 - 6144; }
    else                   { src = mlp_w2; dst = mlp2T; NT = 16; K = 2048; N = 512;  rel = rel0 - 12288; }
    int per = NT * (K / 32);
    int layer = rel / per, r2 = rel - layer * per;
    int nt = r2 % NT, kt = r2 / NT;
    src += (size_t)layer * K * N;
    dst += (size_t)layer * N * K;
    int n0 = nt * 32, k0 = kt * 32;
    int lx = tid & 31, ly = tid >> 5;
    #pragma unroll
    for (int i = 0; i < 32; i += 8)
        tile[ly + i][lx] = src[(size_t)(k0 + ly + i) * N + n0 + lx];
    __syncthreads();
    if (tid < 128) {
        int row = tid >> 2, c = tid & 3;
        short8 o;
        #pragma unroll
        for (int j = 0; j < 8; j++) o[j] = f2bf(tile[c * 8 + j][row]);
        *(short8*)(dst + (size_t)(n0 + row) * K + k0 + c * 8) = o;
    }
}

// ---------------------------------------------------------------------------
// conv_fused: unchanged.
__global__ __launch_bounds__(256, 2) void conv_fused(
    const short* __restrict__ xbf, const short* __restrict__ wbf,
    const float* __restrict__ cb, const float* __restrict__ tg,
    const float* __restrict__ tb, const float* __restrict__ gb,
    float* __restrict__ h) {
    __shared__ short As[64 * 32];
    __shared__ short Bs[512 * 32];
    __shared__ float redsum[4][64], redss[4][64];
    __shared__ float mu_s[64], inv_s[64];
    int bt = blockIdx.x, b = bt >> 5, t = bt & 31;
    int tid = threadIdx.x;
    int wave = tid >> 6, lane = tid & 63, quad = lane >> 4, l16 = lane & 15;

    int rowA = tid >> 2;
    int cA = (tid & 3) ^ ((rowA >> 1) & 3);
    int hn = rowA >> 3, wn2 = rowA & 7;
    long long baseA = (((long long)(b * 32 + t - 2) * 3) << 12)
                      + (long long)(hn * 8) * 64 + wn2 * 8;

    f32x4 acc[4][8];
    #pragma unroll
    for (int mt = 0; mt < 4; mt++)
        #pragma unroll
        for (int nt = 0; nt < 8; nt++) acc[mt][nt] = (f32x4){0.f, 0.f, 0.f, 0.f};

    for (int k0 = 0; k0 < 576; k0 += 32) {
        #pragma unroll
        for (int e = 0; e < 8; e++) {
            int s = e * 256 + tid;
            int n = s >> 2;
            int c = (s & 3) ^ ((n >> 1) & 3);
            async16(wbf + (size_t)n * 576 + k0 + c * 8, Bs + s * 8);
        }
        {
            int ks = (k0 >> 3) + cA;
            int ch = (ks >= 24) + (ks >= 48);
            int r = ks - ch * 24;
            int kt = r >> 3, ph = r & 7;
            short8 v8 = (short8){0, 0, 0, 0, 0, 0, 0, 0};
            if (t + kt >= 2)
                v8 = *(const short8*)(xbf + baseA
                        + ((long long)(kt * 3 + ch) << 12) + ph * 64);
            *(short8*)(As + tid * 8) = v8;
        }
        __syncthreads();
        short8 af[4], bf[8];
        #pragma unroll
        for (int mt = 0; mt < 4; mt++) {
            int row = mt * 16 + l16;
            int pc = quad ^ ((row >> 1) & 3);
            af[mt] = *(const short8*)(As + row * 32 + pc * 8);
        }
        #pragma unroll
        for (int nt = 0; nt < 8; nt++) {
            int row = wave * 128 + nt * 16 + l16;
            int pc = quad ^ ((row >> 1) & 3);
            bf[nt] = *(const short8*)(Bs + row * 32 + pc * 8);
        }
        #pragma unroll
        for (int mt = 0; mt < 4; mt++)
            #pragma unroll
            for (int nt = 0; nt < 8; nt++)
                acc[mt][nt] = __builtin_amdgcn_mfma_f32_16x16x32_bf16(
                    af[mt], bf[nt], acc[mt][nt], 0, 0, 0);
        __syncthreads();
    }

    float cbn[8], tgn[8], tbn[8], Gn[8], Ben[8];
    #pragma unroll
    for (int nt = 0; nt < 8; nt++) {
        int n = wave * 128 + nt * 16 + l16;
        cbn[nt] = cb[n]; tgn[nt] = tg[n]; tbn[nt] = tb[n];
        Gn[nt]  = 1.f + 0.5f * gb[bt * 1024 + n];
        Ben[nt] = 0.5f * gb[bt * 1024 + 512 + n];
    }
    #pragma unroll
    for (int mt = 0; mt < 4; mt++)
        #pragma unroll
        for (int reg = 0; reg < 4; reg++) {
            float s = 0.f, ss = 0.f;
            #pragma unroll
            for (int nt = 0; nt < 8; nt++) {
                float v = acc[mt][nt][reg] + cbn[nt];
                s += v; ss += v * v;
            }
            #pragma unroll
            for (int o = 1; o < 16; o <<= 1) {
                s  += __shfl_xor(s, o, 64);
                ss += __shfl_xor(ss, o, 64);
            }
            if (l16 == 0) {
                int m = mt * 16 + quad * 4 + reg;
                redsum[wave][m] = s; redss[wave][m] = ss;
            }
        }
    __syncthreads();
    if (tid < 64) {
        float S  = redsum[0][tid] + redsum[1][tid] + redsum[2][tid] + redsum[3][tid];
        float SS = redss[0][tid] + redss[1][tid] + redss[2][tid] + redss[3][tid];
        float mu = S * (1.f / 512.f);
        float var = SS * (1.f / 512.f) - mu * mu;
        mu_s[tid] = mu; inv_s[tid] = rsqrtf(var + EPS);
    }
    __syncthreads();
    float hacc[8] = {0.f, 0.f, 0.f, 0.f, 0.f, 0.f, 0.f, 0.f};
    #pragma unroll
    for (int mt = 0; mt < 4; mt++)
        #pragma unroll
        for (int reg = 0; reg < 4; reg++) {
            int m = mt * 16 + quad * 4 + reg;
            float mu = mu_s[m], inv = inv_s[m];
            #pragma unroll
            for (int nt = 0; nt < 8; nt++) {
                float v = acc[mt][nt][reg] + cbn[nt];
                hacc[nt] += (v - mu) * inv;
            }
        }
    #pragma unroll
    for (int nt = 0; nt < 8; nt++) {
        hacc[nt] += __shfl_xor(hacc[nt], 16, 64);
        hacc[nt] += __shfl_xor(hacc[nt], 32, 64);
    }
    if (quad == 0)
        #pragma unroll
        for (int nt = 0; nt < 8; nt++) {
            int n = wave * 128 + nt * 16 + l16;
            h[bt * 512 + n] = Gn[nt] * (tgn[nt] * (hacc[nt] * (1.f / 64.f)) + tbn[nt])
                              + Ben[nt];
        }
}

// ---------------------------------------------------------------------------
// Phase A (WGs 0-7): attn for head hh + fused proj K-slice -> atomicAdd tgt.
// yv never leaves LDS. LN is single-read (row held in registers).
// ---------------------------------------------------------------------------
__device__ __forceinline__ void attn_proj_phase(
    char* smem, int g, int hh, int tid,
    const float* __restrict__ in, const float* __restrict__ lng,
    const float* __restrict__ lnb, const short* __restrict__ Bw,
    const float* __restrict__ bias, const float* __restrict__ ropeS,
    const float* __restrict__ ropeC, const short* __restrict__ Pw,
    const float* __restrict__ rsPtr, float* __restrict__ tgt) {
    float* mu_s = (float*)(smem + 65536);
    float* inv_s = (float*)(smem + 65664);
    short* As = (short*)smem;                      // 32 KB
    short* BsB[2] = {(short*)(smem + 32768), (short*)(smem + 45056)};  // 12 KB ea
    float (*qsf)[64] = (float(*)[64])(smem);
    float (*ksf)[64] = (float(*)[64])(smem + 8192);
    short* vT  = (short*)(smem + 16384);
    short* qrb = (short*)(smem + 20480);
    short* krb = (short*)(smem + 24576);
    float (*att)[33] = (float(*)[33])(smem + 28672);
    short* yv_s = (short*)(smem + 28672);          // 32x64 bf16, XOR-swizzled
    short* pA  = (short*)(smem + 36864);
    short* Ws  = (short*)(smem + 32768);           // proj B staging (32 KB)
    int m0 = g * 32;
    int wave = tid >> 6, lane = tid & 63, quad = lane >> 4, l16 = lane & 15;
    // kqv B prefetch k0=0 (overlaps LN)
    #pragma unroll
    for (int e = 0; e < 3; e++) {
        int p = e * 256 + tid;
        int row = p >> 2, seg = (p & 3) ^ ((row >> 1) & 3);
        int n = ((row >> 6) << 9) + hh * 64 + (row & 63);
        async16(Bw + (size_t)n * 512 + seg * 8, BsB[0] + p * 8);
    }
    // LN single-read: thread owns row rowL, cols l8*64..+63 (64 regs)
    int rowL = tid >> 3, l8 = tid & 7;
    float hreg[64];
    {
        const float* hp = in + (size_t)(m0 + rowL) * 512 + l8 * 64;
        float s = 0.f, ss = 0.f;
        #pragma unroll
        for (int i2 = 0; i2 < 32; i2++) {
            float2 v = ald2(hp + i2 * 2);
            hreg[i2 * 2] = v.x; hreg[i2 * 2 + 1] = v.y;
            s += v.x + v.y;
            ss += v.x * v.x + v.y * v.y;
        }
        s += __shfl_xor(s, 1, 64); ss += __shfl_xor(ss, 1, 64);
        s += __shfl_xor(s, 2, 64); ss += __shfl_xor(ss, 2, 64);
        s += __shfl_xor(s, 4, 64); ss += __shfl_xor(ss, 4, 64);
        if (l8 == 0) {
            float mu = s * (1.f / 512.f);
            float var = ss * (1.f / 512.f) - mu * mu;
            mu_s[rowL] = mu;
            inv_s[rowL] = rsqrtf(var + EPS);
        }
    }
    __syncthreads();
    {
        float mu = mu_s[rowL], inv = inv_s[rowL];
        #pragma unroll
        for (int j = 0; j < 8; j++) {
            int cc = l8 * 8 + j;
            short8 o;
            #pragma unroll
            for (int q2 = 0; q2 < 8; q2++)
                o[q2] = f2bf((hreg[j * 8 + q2] - mu) * inv * lng[cc * 8 + q2]
                             + lnb[cc * 8 + q2]);
            *(short8*)(As + (rowL * 64 + (cc ^ (rowL & 7))) * 8) = o;
        }
    }
    __syncthreads();
    f32x4 acc[2][3];
    #pragma unroll
    for (int m2 = 0; m2 < 2; m2++)
        #pragma unroll
        for (int gg = 0; gg < 3; gg++) acc[m2][gg] = (f32x4){0.f, 0.f, 0.f, 0.f};
    for (int it = 0; it < 16; it++) {
        short* Bsc = BsB[it & 1];
        if (it < 15) {
            int k0n = (it + 1) * 32;
            short* Bsn = BsB[(it + 1) & 1];
            #pragma unroll
            for (int e = 0; e < 3; e++) {
                int p = e * 256 + tid;
                int row = p >> 2, seg = (p & 3) ^ ((row >> 1) & 3);
                int n = ((row >> 6) << 9) + hh * 64 + (row & 63);
                async16(Bw + (size_t)n * 512 + k0n + seg * 8, Bsn + p * 8);
            }
        }
        int cc = it * 4 + quad;
        short8 af[2], bf[3];
        #pragma unroll
        for (int m2 = 0; m2 < 2; m2++) {
            int row = m2 * 16 + l16;
            af[m2] = *(const short8*)(As + (row * 64 + (cc ^ (row & 7))) * 8);
        }
        #pragma unroll
        for (int gg = 0; gg < 3; gg++) {
            int row = gg * 64 + wave * 16 + l16;
            int pc = quad ^ ((row >> 1) & 3);
            bf[gg] = *(const short8*)(Bsc + (row * 4 + pc) * 8);
        }
        #pragma unroll
        for (int m2 = 0; m2 < 2; m2++)
            #pragma unroll
            for (int gg = 0; gg < 3; gg++)
                acc[m2][gg] = __builtin_amdgcn_mfma_f32_16x16x32_bf16(
                    af[m2], bf[gg], acc[m2][gg], 0, 0, 0);
        __syncthreads();
    }
    // epilogue: k,q fp32 -> LDS; v -> vT bf16
    float bb0 = bias[hh * 64 + wave * 16 + l16];
    float bb1 = bias[512 + hh * 64 + wave * 16 + l16];
    float bb2 = bias[1024 + hh * 64 + wave * 16 + l16];
    int dcol = wave * 16 + l16;
    #pragma unroll
    for (int m2 = 0; m2 < 2; m2++)
        #pragma unroll
        for (int reg = 0; reg < 4; reg++) {
            int tkn = m2 * 16 + quad * 4 + reg;
            ksf[tkn][dcol] = acc[m2][0][reg] + bb0;
            qsf[tkn][dcol] = acc[m2][1][reg] + bb1;
            vT[dcol * 32 + (((tkn >> 3) ^ (dcol & 3)) << 3) + (tkn & 7)]
                = f2bf(acc[m2][2][reg] + bb2);
        }
    __syncthreads();
    // RoPE (table)
    #pragma unroll
    for (int e = 0; e < 8; e++) {
        int idx = e * 256 + tid;
        int t = idx >> 6, d = idx & 63, j = d & 31;
        float sv = ropeS[t * 32 + j], cv = ropeC[t * 32 + j];
        float qv = qsf[t][d], kv = ksf[t][d];
        float qo = qsf[t][d ^ 32], ko = ksf[t][d ^ 32];
        float rq = (d < 32) ? -qo : qo;
        float rk = (d < 32) ? -ko : ko;
        int addr = t * 64 + (((d >> 3) ^ (t & 7)) << 3) + (d & 7);
        qrb[addr] = f2bf(qv * cv + rq * sv);
        krb[addr] = f2bf(kv * cv + rk * sv);
    }
    __syncthreads();
    int mw = wave & 1, nw = wave >> 1;
    // QK^T via MFMA
    {
        f32x4 sc = (f32x4){0.f, 0.f, 0.f, 0.f};
        #pragma unroll
        for (int kc = 0; kc < 2; kc++) {
            int rq = mw * 16 + l16;
            int rk = nw * 16 + l16;
            short8 aq = *(const short8*)(qrb + rq * 64 + ((((kc << 2) + quad) ^ (rq & 7)) << 3));
            short8 bk = *(const short8*)(krb + rk * 64 + ((((kc << 2) + quad) ^ (rk & 7)) << 3));
            sc = __builtin_amdgcn_mfma_f32_16x16x32_bf16(aq, bk, sc, 0, 0, 0);
        }
        #pragma unroll
        for (int reg = 0; reg < 4; reg++) {
            int qt = mw * 16 + quad * 4 + reg;
            int kt = nw * 16 + l16;
            att[qt][kt] = (kt > qt) ? -1e30f : sc[reg] * 0.125f;
        }
    }
    __syncthreads();
    // softmax
    {
        int row = tid >> 3, gg = tid & 7;
        float v0 = att[row][gg * 4], v1 = att[row][gg * 4 + 1];
        float v2 = att[row][gg * 4 + 2], v3 = att[row][gg * 4 + 3];
        float mx = fmaxf(fmaxf(v0, v1), fmaxf(v2, v3));
        mx = fmaxf(mx, __shfl_xor(mx, 1, 64));
        mx = fmaxf(mx, __shfl_xor(mx, 2, 64));
        mx = fmaxf(mx, __shfl_xor(mx, 4, 64));
        float e0 = expf(v0 - mx), e1 = expf(v1 - mx);
        float e2 = expf(v2 - mx), e3 = expf(v3 - mx);
        float s = e0 + e1 + e2 + e3;
        s += __shfl_xor(s, 1, 64);
        s += __shfl_xor(s, 2, 64);
        s += __shfl_xor(s, 4, 64);
        float inv = 1.f / s;
        short* pp = pA + row * 32 + gg * 4;
        pp[0] = f2bf(e0 * inv); pp[1] = f2bf(e1 * inv);
        pp[2] = f2bf(e2 * inv); pp[3] = f2bf(e3 * inv);
    }
    __syncthreads();
    // PV via MFMA -> yv_s (XOR-swizzled, overlays dead att)
    {
        int rp = mw * 16 + l16;
        short8 ap = *(const short8*)(pA + rp * 32 + quad * 8);
        #pragma unroll
        for (int i = 0; i < 2; i++) {
            int nt = (wave >> 1) * 2 + i;
            int rv = nt * 16 + l16;
            short8 bv = *(const short8*)(vT + rv * 32 + (((quad ^ (rv & 3))) << 3));
            f32x4 o = (f32x4){0.f, 0.f, 0.f, 0.f};
            o = __builtin_amdgcn_mfma_f32_16x16x32_bf16(ap, bv, o, 0, 0, 0);
            #pragma unroll
            for (int reg = 0; reg < 4; reg++) {
                int t = mw * 16 + quad * 4 + reg;
                int d = nt * 16 + l16;
                yv_s[t * 64 + (d ^ ((t & 7) << 3))] = f2bf(o[reg]);
            }
        }
    }
    // ---- fused proj K-slice: yv_h (32x64) @ Wproj[hh*64..+64, :] ----
    float rsv = *rsPtr;
    __syncthreads();
    #pragma unroll
    for (int half = 0; half < 2; half++) {
        // stage Wproj[n = half*256..+256][k = hh*64..+64], source pre-swizzled
        #pragma unroll
        for (int e = 0; e < 8; e++) {
            int p = e * 256 + tid;
            int row = p >> 3, c = p & 7;
            async16(Pw + (size_t)(half * 256 + row) * 512 + hh * 64
                        + ((c ^ (row & 7)) * 8), Ws + p * 8);
        }
        __syncthreads();
        f32x4 pacc[2][4];
        #pragma unroll
        for (int m2 = 0; m2 < 2; m2++)
            #pragma unroll
            for (int nt = 0; nt < 4; nt++) pacc[m2][nt] = (f32x4){0.f, 0.f, 0.f, 0.f};
        #pragma unroll
        for (int kc = 0; kc < 2; kc++) {
            short8 afr[2];
            #pragma unroll
            for (int m2 = 0; m2 < 2; m2++) {
                int ra = m2 * 16 + l16;
                afr[m2] = *(const short8*)(yv_s + ra * 64
                            + (((kc * 4 + quad) ^ (ra & 7)) << 3));
            }
            #pragma unroll
            for (int nt = 0; nt < 4; nt++) {
                int rb = wave * 64 + nt * 16 + l16;
                short8 bfr = *(const short8*)(Ws + (rb * 8
                            + ((kc * 4 + quad) ^ (rb & 7))) * 8);
                #pragma unroll
                for (int m2 = 0; m2 < 2; m2++)
                    pacc[m2][nt] = __builtin_amdgcn_mfma_f32_16x16x32_bf16(
                        afr[m2], bfr, pacc[m2][nt], 0, 0, 0);
            }
        }
        #pragma unroll
        for (int m2 = 0; m2 < 2; m2++)
            #pragma unroll
            for (int nt = 0; nt < 4; nt++)
                #pragma unroll
                for (int reg = 0; reg < 4; reg++) {
                    int m = m0 + m2 * 16 + quad * 4 + reg;
                    int n = half * 256 + wave * 64 + nt * 16 + l16;
                    atomicAdd(&tgt[(size_t)m * 512 + n], rsv * pacc[m2][nt][reg]);
                }
        __syncthreads();
    }
}

// ---------------------------------------------------------------------------
// Phase A aux (WGs 8-15): residual base (in + rs*proj_bias) -> atomicAdd tgt;
// zero 1/8 slice of zz.
// ---------------------------------------------------------------------------
__device__ __forceinline__ void phaseA_aux(
    int g, int j, int tid,
    const float* __restrict__ in, const float* __restrict__ pb, float rsv,
    float* __restrict__ tgt, float* __restrict__ zz) {
    int m0g = g * 16384;
    {
        float* zp = zz + m0g + j * 2048 + tid * 8;
        astu(zp, 0ull); astu(zp + 2, 0ull); astu(zp + 4, 0ull); astu(zp + 6, 0ull);
    }
    int r = 4 * j + (tid >> 6);
    int c0 = (tid & 63) * 8;
    const float* ip = in + m0g + r * 512 + c0;
    float* tp = tgt + m0g + r * 512 + c0;
    #pragma unroll
    for (int e = 0; e < 4; e++) {
        float2 v = ald2(ip + e * 2);
        atomicAdd(tp + e * 2,     v.x + rsv * pb[c0 + e * 2]);
        atomicAdd(tp + e * 2 + 1, v.y + rsv * pb[c0 + e * 2 + 1]);
    }
}

// ---------------------------------------------------------------------------
// Phase B (all 16 WGs): LN2 + mlp1 n-slice(128) + GELU + fused mlp2 K-slice
// -> atomicAdd tgt. Also residual base (2 rows/WG) and zero duty.
// ---------------------------------------------------------------------------
__device__ __forceinline__ void mlp_phase(
    char* smem, int g, int wgl, int tid,
    const float* __restrict__ in, const float* __restrict__ lng,
    const float* __restrict__ lnb, const short* __restrict__ B1,
    const float* __restrict__ b1, const short* __restrict__ B2,
    const float* __restrict__ b2, const float* __restrict__ rsPtr,
    float* __restrict__ tgt, float* __restrict__ zz) {
    short* As = (short*)smem;                // 32KB LN-staged
    short* Bs = (short*)(smem + 32768);      // 32KB mlp1 B
    short* gs = (short*)smem;                // gelu tile 8KB (after As dead)
    short* W2 = (short*)(smem + 32768);      // 32KB mlp2 B quarter
    float* mu_s = (float*)(smem + 65536);
    float* inv_s = (float*)(smem + 65664);
    int m0 = g * 32, n0 = wgl * 128, m0g = g * 16384;
    float rsv = *rsPtr;
    // B1 prefetch it=0
    #pragma unroll
    for (int e = 0; e < 8; e++) {
        int p = e * 256 + tid;
        int row = p >> 4, seg = (p & 15) ^ (row & 15);
        async16(B1 + (size_t)(n0 + row) * 512 + seg * 8, Bs + p * 8);
    }
    // zero duty (1024 f)
    {
        float* zp = zz + m0g + wgl * 1024 + tid * 4;
        astu(zp, 0ull); astu(zp + 2, 0ull);
    }
    // residual base: rows 2wgl, 2wgl+1
    {
        int r = 2 * wgl + (tid >> 7);
        int c0 = (tid & 127) * 4;
        const float* ip = in + m0g + r * 512 + c0;
        float* tp = tgt + m0g + r * 512 + c0;
        #pragma unroll
        for (int e = 0; e < 2; e++) {
            float2 v = ald2(ip + e * 2);
            atomicAdd(tp + e * 2,     v.x + rsv * b2[c0 + e * 2]);
            atomicAdd(tp + e * 2 + 1, v.y + rsv * b2[c0 + e * 2 + 1]);
        }
    }
    // LN single-read
    int rowL = tid >> 3, l8 = tid & 7;
    float hreg[64];
    {
        const float* hp = in + (size_t)(m0 + rowL) * 512 + l8 * 64;
        float s = 0.f, ss = 0.f;
        #pragma unroll
        for (int i2 = 0; i2 < 32; i2++) {
            float2 v = ald2(hp + i2 * 2);
            hreg[i2 * 2] = v.x; hreg[i2 * 2 + 1] = v.y;
            s += v.x + v.y;
            ss += v.x * v.x + v.y * v.y;
        }
        s += __shfl_xor(s, 1, 64); ss += __shfl_xor(ss, 1, 64);
        s += __shfl_xor(s, 2, 64); ss += __shfl_xor(ss, 2, 64);
        s += __shfl_xor(s, 4, 64); ss += __shfl_xor(ss, 4, 64);
        if (l8 == 0) {
            float mu = s * (1.f / 512.f);
            float var = ss * (1.f / 512.f) - mu * mu;
            mu_s[rowL] = mu;
            inv_s[rowL] = rsqrtf(var + EPS);
        }
    }
    __syncthreads();
    {
        float mu = mu_s[rowL], inv = inv_s[rowL];
        #pragma unroll
        for (int j = 0; j < 8; j++) {
            int cc = l8 * 8 + j;
            short8 o;
            #pragma unroll
            for (int q2 = 0; q2 < 8; q2++)
                o[q2] = f2bf((hreg[j * 8 + q2] - mu) * inv * lng[cc * 8 + q2]
                             + lnb[cc * 8 + q2]);
            *(short8*)(As + (rowL * 64 + (cc ^ (rowL & 7))) * 8) = o;
        }
    }
    __syncthreads();
    int wave = tid >> 6, lane = tid & 63, quad = lane >> 4, l16 = lane & 15;
    f32x4 acc[2][2];
    #pragma unroll
    for (int a2 = 0; a2 < 2; a2++)
        #pragma unroll
        for (int b2i = 0; b2i < 2; b2i++) acc[a2][b2i] = (f32x4){0.f, 0.f, 0.f, 0.f};
    for (int it = 0; it < 4; it++) {
        int k0 = it * 128;
        #pragma unroll
        for (int ksub = 0; ksub < 4; ksub++) {
            int ccb = ksub * 4 + quad;
            short8 af[2], bf[2];
            #pragma unroll
            for (int m2 = 0; m2 < 2; m2++) {
                int row = m2 * 16 + l16;
                int cc = (k0 >> 3) + ccb;
                af[m2] = *(const short8*)(As + (row * 64 + (cc ^ (row & 7))) * 8);
            }
            #pragma unroll
            for (int n2 = 0; n2 < 2; n2++) {
                int row = wave * 32 + n2 * 16 + l16;
                bf[n2] = *(const short8*)(Bs + (row * 16 + (ccb ^ (row & 15))) * 8);
            }
            #pragma unroll
            for (int m2 = 0; m2 < 2; m2++)
                #pragma unroll
                for (int n2 = 0; n2 < 2; n2++)
                    acc[m2][n2] = __builtin_amdgcn_mfma_f32_16x16x32_bf16(
                        af[m2], bf[n2], acc[m2][n2], 0, 0, 0);
        }
        __syncthreads();
        if (it < 3) {
            int k0n = (it + 1) * 128;
            #pragma unroll
            for (int e = 0; e < 8; e++) {
                int p = e * 256 + tid;
                int row = p >> 4, seg = (p & 15) ^ (row & 15);
                async16(B1 + (size_t)(n0 + row) * 512 + k0n + seg * 8, Bs + p * 8);
            }
            __syncthreads();
        }
    }
    // GELU -> gs (32x128 bf16, XOR-swizzled; As is dead past last barrier)
    #pragma unroll
    for (int m2 = 0; m2 < 2; m2++)
        #pragma unroll
        for (int n2 = 0; n2 < 2; n2++)
            #pragma unroll
            for (int reg = 0; reg < 4; reg++) {
                int mr = m2 * 16 + quad * 4 + reg;
                int nr = wave * 32 + n2 * 16 + l16;
                float v = acc[m2][n2][reg] + b1[n0 + nr];
                v = 0.5f * v * (1.f + erff(v * 0.70710678118f));
                gs[mr * 128 + (nr ^ ((mr & 7) << 3))] = f2bf(v);
            }
    __syncthreads();
    // ---- fused mlp2 K-slice: gelu (32x128) @ W2[k=wgl*128..+128, :] ----
    #pragma unroll
    for (int nq = 0; nq < 4; nq++) {
        #pragma unroll
        for (int e = 0; e < 8; e++) {
            int p = e * 256 + tid;
            int row = p >> 4, c = p & 15;
            async16(B2 + (size_t)(nq * 128 + row) * 2048 + n0
                        + ((c ^ (row & 15)) * 8), W2 + p * 8);
        }
        __syncthreads();
        f32x4 qacc[2][2];
        #pragma unroll
        for (int m2 = 0; m2 < 2; m2++)
            #pragma unroll
            for (int n2 = 0; n2 < 2; n2++) qacc[m2][n2] = (f32x4){0.f, 0.f, 0.f, 0.f};
        #pragma unroll
        for (int ks = 0; ks < 4; ks++) {
            short8 afr[2];
            #pragma unroll
            for (int m2 = 0; m2 < 2; m2++) {
                int ra = m2 * 16 + l16;
                afr[m2] = *(const short8*)(gs + ra * 128
                            + (((ks * 4 + quad) ^ (ra & 7)) << 3));
            }
            #pragma unroll
            for (int n2 = 0; n2 < 2; n2++) {
                int rb = wave * 32 + n2 * 16 + l16;
                short8 bfr = *(const short8*)(W2 + (rb * 16
                            + ((ks * 4 + quad) ^ (rb & 15))) * 8);
                #pragma unroll
                for (int m2 = 0; m2 < 2; m2++)
                    qacc[m2][n2] = __builtin_amdgcn_mfma_f32_16x16x32_bf16(
                        afr[m2], bfr, qacc[m2][n2], 0, 0, 0);
            }
        }
        #pragma unroll
        for (int m2 = 0; m2 < 2; m2++)
            #pragma unroll
            for (int n2 = 0; n2 < 2; n2++)
                #pragma unroll
                for (int reg = 0; reg < 4; reg++) {
                    int m = m0 + m2 * 16 + quad * 4 + reg;
                    int n = nq * 128 + wave * 32 + n2 * 16 + l16;
                    atomicAdd(&tgt[(size_t)m * 512 + n], rsv * qacc[m2][n2][reg]);
                }
        __syncthreads();
    }
}

// ---------------------------------------------------------------------------
__device__ __forceinline__ void head_phase(
    char* smem, int token, int tid,
    const float* __restrict__ h, const float* __restrict__ g,
    const float* __restrict__ bb, const float* __restrict__ w,
    const float* __restrict__ bias0, float* __restrict__ out) {
    float* red = (float*)smem;
    float v0 = ald1(h + (size_t)token * 512 + tid);
    float v1 = ald1(h + (size_t)token * 512 + tid + 256);
    float s  = block_reduce_sum_256(v0 + v1, red);
    float ss = block_reduce_sum_256(v0 * v0 + v1 * v1, red);
    float mu = s * (1.f / 512.f);
    float var = ss * (1.f / 512.f) - mu * mu;
    float inv = rsqrtf(var + EPS);
    float n0 = (v0 - mu) * inv * g[tid] + bb[tid];
    float n1 = (v1 - mu) * inv * g[tid + 256] + bb[tid + 256];
    float dot = block_reduce_sum_256(n0 * w[tid] + n1 * w[tid + 256], red);
    if (tid == 0) out[token] = dot + bias0[0];
}

// ---------------------------------------------------------------------------
// mega v5: 16 groups x 16 WGs = 256 WGs (R3's proven geometry), but only
// TWO fused phases per layer (12 barriers total, was 24). Split-K fusion via
// f32 atomicAdd into a 3-buffer rotation (each phase zeroes the buffer that
// becomes the target two phases later). yv/mbuf never touch global memory.
// ---------------------------------------------------------------------------
__global__ __launch_bounds__(256) void mega(
    float* __restrict__ b0, float* __restrict__ b1p, float* __restrict__ b2p,
    const float* __restrict__ ropeS, const float* __restrict__ ropeC,
    const short* __restrict__ kqvT, const short* __restrict__ projT,
    const short* __restrict__ mlp1T, const short* __restrict__ mlp2T,
    const float* __restrict__ ln1_g, const float* __restrict__ ln1_b,
    const float* __restrict__ kqv_b, const float* __restrict__ proj_b,
    const float* __restrict__ ln2_g, const float* __restrict__ ln2_b,
    const float* __restrict__ mlp_b1, const float* __restrict__ mlp_b2,
    const float* __restrict__ rs_attn, const float* __restrict__ rs_mlp,
    const float* __restrict__ head_g, const float* __restrict__ head_b,
    const float* __restrict__ head_w, const float* __restrict__ head_bs,
    float* __restrict__ out, unsigned* __restrict__ bar) {
    __shared__ char smem[65792] __attribute__((aligned(16)));
    int wg = blockIdx.x, tid = threadIdx.x;
    int g = wg >> 4, wgl = wg & 15;
    unsigned* flag = bar + g * 32;
    unsigned goal = 0;
    float* p0 = b0; float* p1 = b1p; float* p2 = b2p;

    for (int i = 0; i < 6; i++) {
        // ---- Phase A: attn + proj split-K (WGs 0-7) / base + zero (8-15) ----
        if (wgl < 8)
            attn_proj_phase(smem, g, wgl, tid, p0,
                ln1_g + i * 512, ln1_b + i * 512,
                kqvT + (size_t)i * 786432, kqv_b + i * 1536,
                ropeS, ropeC,
                projT + (size_t)i * 262144, rs_attn + i, p1);
        else
            phaseA_aux(g, wgl - 8, tid, p0, proj_b + i * 512, rs_attn[i], p1, p2);
        goal += 16; group_sync(flag, goal);
        // ---- Phase B: LN2 + mlp1 + GELU + mlp2 split-K (all 16 WGs) ----
        mlp_phase(smem, g, wgl, tid, p1,
            ln2_g + i * 512, ln2_b + i * 512,
            mlp1T + (size_t)i * 1048576, mlp_b1 + i * 2048,
            mlp2T + (size_t)i * 1048576, mlp_b2 + i * 512,
            rs_mlp + i, p2, p0);
        goal += 16; group_sync(flag, goal);
        // rotate buffers (period 3)
        float* t = p0; p0 = p2; p2 = p1; p1 = t;
    }
    // ---- head: 2 tokens per WG; result lives in p0 ----
    head_phase(smem, g * 32 + wgl * 2, tid, p0, head_g, head_b, head_w, head_bs, out);
    head_phase(smem, g * 32 + wgl * 2 + 1, tid, p0, head_g, head_b, head_w, head_bs, out);
}

// ---------------------------------------------------------------------------
extern "C" void kernel_launch(void* const* d_in, const int* in_sizes, int n_in,
                              void* d_out, int out_size, void* d_ws, size_t ws_size,
                              hipStream_t stream) {
    const float* x       = (const float*)d_in[0];
    const float* z       = (const float*)d_in[1];
    const float* conv_w  = (const float*)d_in[2];
    const float* conv_b  = (const float*)d_in[3];
    const float* tok_g   = (const float*)d_in[4];
    const float* tok_b   = (const float*)d_in[5];
    const float* film_w  = (const float*)d_in[6];
    const float* film_b  = (const float*)d_in[7];
    const float* ln1_g   = (const float*)d_in[8];
    const float* ln1_b   = (const float*)d_in[9];
    const float* kqv_w   = (const float*)d_in[10];
    const float* kqv_b   = (const float*)d_in[11];
    const float* proj_w  = (const float*)d_in[12];
    const float* proj_b  = (const float*)d_in[13];
    const float* ln2_g   = (const float*)d_in[14];
    const float* ln2_b   = (const float*)d_in[15];
    const float* mlp_w1  = (const float*)d_in[16];
    const float* mlp_b1  = (const float*)d_in[17];
    const float* mlp_w2  = (const float*)d_in[18];
    const float* mlp_b2  = (const float*)d_in[19];
    const float* rs_attn = (const float*)d_in[20];
    const float* rs_mlp  = (const float*)d_in[21];
    const float* head_g  = (const float*)d_in[22];
    const float* head_b  = (const float*)d_in[23];
    const float* head_w  = (const float*)d_in[24];
    const float* head_bs = (const float*)d_in[25];
    float* out = (float*)d_out;

    float* ws = (float*)d_ws;
    float* gb    = ws;                  // 524288 f (FiLM)
    float* h     = gb + 524288;         // 262144 f (buffer R0)
    float* ropeS = h + 262144;          // 1024 f
    float* ropeC = ropeS + 1024;        // 1024 f
    short* sb = (short*)(ropeC + 1024);
    short* wbf   = sb;                 // 294912
    short* kqvT  = wbf   + 294912;     // 4718592
    short* projT = kqvT  + 4718592;    // 1572864
    short* mlp1T = projT + 1572864;    // 6291456
    short* mlp2T = mlp1T + 6291456;    // 6291456
    short* r12   = mlp2T + 6291456;    // 1310720 shorts = 2.62 MB region
    float* R1 = (float*)r12;           // 262144 f
    float* R2 = R1 + 262144;           // 262144 f
    short* xbf   = r12 + 1310720;      // 6291456
    unsigned* bar = (unsigned*)(xbf + 6291456);   // 512 u32

    prep_all<<<23428, 256, 0, stream>>>(
        z, film_w, film_b, gb, conv_w, wbf, x, xbf, ropeS, ropeC,
        kqv_w, kqvT, proj_w, projT, mlp_w1, mlp1T, mlp_w2, mlp2T, bar, R1);

    conv_fused<<<512, 256, 0, stream>>>(xbf, wbf, conv_b, tok_g, tok_b, gb, h);

    mega<<<256, 256, 0, stream>>>(
        h, R1, R2, ropeS, ropeC, kqvT, projT, mlp1T, mlp2T,
        ln1_g, ln1_b, kqv_b, proj_b, ln2_g, ln2_b, mlp_b1, mlp_b2,
        rs_attn, rs_mlp, head_g, head_b, head_w, head_bs, out, bar);
}

// Round 7
// 590.099 us; speedup vs baseline: 1.7435x; 1.0081x over previous
//
#include <hip/hip_runtime.h>
#include <math.h>

#define EPS 1e-5f

typedef __attribute__((ext_vector_type(8))) short short8;
typedef __attribute__((ext_vector_type(4))) float f32x4;

#define S_BARRIER() do { __builtin_amdgcn_s_barrier(); \
                         __builtin_amdgcn_sched_barrier(0); } while (0)
#define BAR_LDS() do { asm volatile("s_waitcnt lgkmcnt(0)" ::: "memory"); \
                       S_BARRIER(); } while (0)

__device__ __forceinline__ short f2bf(float f) {
    unsigned u = __float_as_uint(f);
    u += 0x7fffu + ((u >> 16) & 1u);
    return (short)(u >> 16);
}
__device__ __forceinline__ float bf2f(short s) {
    return __uint_as_float(((unsigned)(unsigned short)s) << 16);
}
__device__ __forceinline__ void async16(const void* g, void* l) {
    __builtin_amdgcn_global_load_lds(
        (const __attribute__((address_space(1))) unsigned*)g,
        (__attribute__((address_space(3))) unsigned*)l, 16, 0, 0);
}

// ---------------------------------------------------------------------------
// Agent-scope (coherent-point) load/store helpers for cross-WG data.
// ---------------------------------------------------------------------------
__device__ __forceinline__ unsigned long long aldu(const void* p) {
    return __hip_atomic_load((const unsigned long long*)p, __ATOMIC_RELAXED,
                             __HIP_MEMORY_SCOPE_AGENT);
}
__device__ __forceinline__ void astu(void* p, unsigned long long v) {
    __hip_atomic_store((unsigned long long*)p, v, __ATOMIC_RELAXED,
                       __HIP_MEMORY_SCOPE_AGENT);
}
__device__ __forceinline__ float2 ald2(const float* p) {
    unsigned long long u = aldu(p);
    float2 f;
    f.x = __uint_as_float((unsigned)u);
    f.y = __uint_as_float((unsigned)(u >> 32));
    return f;
}
__device__ __forceinline__ float ald1(const float* p) {
    return __uint_as_float(__hip_atomic_load((const unsigned*)p, __ATOMIC_RELAXED,
                                             __HIP_MEMORY_SCOPE_AGENT));
}

// ---------------------------------------------------------------------------
// Per-group barrier (16 WGs). Release fetch_add + relaxed polling.
// ---------------------------------------------------------------------------
__device__ __forceinline__ void group_sync(unsigned* flag, unsigned goal) {
    __syncthreads();
    if (threadIdx.x == 0) {
        __hip_atomic_fetch_add(flag, 1u, __ATOMIC_RELEASE, __HIP_MEMORY_SCOPE_AGENT);
        unsigned spins = 0;
        while (__hip_atomic_load(flag, __ATOMIC_RELAXED, __HIP_MEMORY_SCOPE_AGENT) < goal) {
            __builtin_amdgcn_s_sleep(1);
            if (++spins > 2000000u) break;   // deadlock bailout
        }
    }
    __syncthreads();
}

// ---------------------------------------------------------------------------
__device__ __forceinline__ float block_reduce_sum_256(float v, float* red) {
    #pragma unroll
    for (int o = 32; o > 0; o >>= 1) v += __shfl_down(v, o, 64);
    __syncthreads();
    if ((threadIdx.x & 63) == 0) red[threadIdx.x >> 6] = v;
    __syncthreads();
    return red[0] + red[1] + red[2] + red[3];
}

// ---------------------------------------------------------------------------
// prep_all: unchanged (zeroes bar + R1).
__global__ __launch_bounds__(256) void prep_all(
    const float* __restrict__ z, const float* __restrict__ fw,
    const float* __restrict__ fb, float* __restrict__ gb,
    const float* __restrict__ conv_w, short* __restrict__ wbf,
    const float* __restrict__ x, short* __restrict__ xbf,
    float* __restrict__ ropeS, float* __restrict__ ropeC,
    const float* __restrict__ kqv_w, short* __restrict__ kqvT,
    const float* __restrict__ proj_w, short* __restrict__ projT,
    const float* __restrict__ mlp_w1, short* __restrict__ mlp1T,
    const float* __restrict__ mlp_w2, short* __restrict__ mlp2T,
    unsigned* __restrict__ bar, float* __restrict__ zbuf) {
    int bi = blockIdx.x, tid = threadIdx.x;
    if (bi == 0) { bar[tid] = 0u; bar[tid + 256] = 0u; }
    if (bi >= 23172) {
        int idx = (bi - 23172) * 256 + tid;
        float4 z4 = {0.f, 0.f, 0.f, 0.f};
        ((float4*)zbuf)[idx] = z4;
        return;
    }
    if (bi < 512) {
        __shared__ float zs[32];
        if (tid < 32) zs[tid] = z[bi * 32 + tid];
        __syncthreads();
        for (int j = tid; j < 1024; j += 256) {
            float acc = fb[j];
            #pragma unroll
            for (int k = 0; k < 32; k++) acc = fmaf(zs[k], fw[k * 1024 + j], acc);
            gb[bi * 1024 + j] = acc;
        }
        return;
    }
    if (bi < 1664) {
        int i = (bi - 512) * 256 + tid;
        wbf[i] = f2bf(conv_w[i]);
        return;
    }
    if (bi < 4736) {
        int i = (bi - 1664) * 256 + tid;
        float4 a = *(const float4*)(x + (size_t)i * 8);
        float4 b = *(const float4*)(x + (size_t)i * 8 + 4);
        short8 o = {f2bf(a.x), f2bf(a.y), f2bf(a.z), f2bf(a.w),
                    f2bf(b.x), f2bf(b.y), f2bf(b.z), f2bf(b.w)};
        *(short8*)(xbf + (size_t)i * 8) = o;
        return;
    }
    if (bi < 4740) {
        int idx = (bi - 4736) * 256 + tid;
        if (idx < 1024) {
            int t = idx >> 5, j = idx & 31;
            float ang = (float)t * expf(-(float)j * (logf(10000.f) / 32.f));
            ropeS[idx] = sinf(ang);
            ropeC[idx] = cosf(ang);
        }
        return;
    }
    __shared__ float tile[32][33];
    int rel0 = bi - 4740;
    const float* src; short* dst; int NT, K, N, rel;
    if (rel0 < 4608)       { src = kqv_w;  dst = kqvT;  NT = 48; K = 512;  N = 1536; rel = rel0; }
    else if (rel0 < 6144)  { src = proj_w; dst = projT; NT = 16; K = 512;  N = 512;  rel = rel0 - 4608; }
    else if (rel0 < 12288) { src = mlp_w1; dst = mlp1T; NT = 64; K = 512;  N = 2048; rel = rel0 - 6144; }
    else                   { src = mlp_w2; dst = mlp2T; NT = 16; K = 2048; N = 512;  rel = rel0 - 12288; }
    int per = NT * (K / 32);
    int layer = rel / per, r2 = rel - layer * per;
    int nt = r2 % NT, kt = r2 / NT;
    src += (size_t)layer * K * N;
    dst += (size_t)layer * N * K;
    int n0 = nt * 32, k0 = kt * 32;
    int lx = tid & 31, ly = tid >> 5;
    #pragma unroll
    for (int i = 0; i < 32; i += 8)
        tile[ly + i][lx] = src[(size_t)(k0 + ly + i) * N + n0 + lx];
    __syncthreads();
    if (tid < 128) {
        int row = tid >> 2, c = tid & 3;
        short8 o;
        #pragma unroll
        for (int j = 0; j < 8; j++) o[j] = f2bf(tile[c * 8 + j][row]);
        *(short8*)(dst + (size_t)(n0 + row) * K + k0 + c * 8) = o;
    }
}

// ---------------------------------------------------------------------------
// conv_fused: unchanged.
__global__ __launch_bounds__(256, 2) void conv_fused(
    const short* __restrict__ xbf, const short* __restrict__ wbf,
    const float* __restrict__ cb, const float* __restrict__ tg,
    const float* __restrict__ tb, const float* __restrict__ gb,
    float* __restrict__ h) {
    __shared__ short As[64 * 32];
    __shared__ short Bs[512 * 32];
    __shared__ float redsum[4][64], redss[4][64];
    __shared__ float mu_s[64], inv_s[64];
    int bt = blockIdx.x, b = bt >> 5, t = bt & 31;
    int tid = threadIdx.x;
    int wave = tid >> 6, lane = tid & 63, quad = lane >> 4, l16 = lane & 15;

    int rowA = tid >> 2;
    int cA = (tid & 3) ^ ((rowA >> 1) & 3);
    int hn = rowA >> 3, wn2 = rowA & 7;
    long long baseA = (((long long)(b * 32 + t - 2) * 3) << 12)
                      + (long long)(hn * 8) * 64 + wn2 * 8;

    f32x4 acc[4][8];
    #pragma unroll
    for (int mt = 0; mt < 4; mt++)
        #pragma unroll
        for (int nt = 0; nt < 8; nt++) acc[mt][nt] = (f32x4){0.f, 0.f, 0.f, 0.f};

    for (int k0 = 0; k0 < 576; k0 += 32) {
        #pragma unroll
        for (int e = 0; e < 8; e++) {
            int s = e * 256 + tid;
            int n = s >> 2;
            int c = (s & 3) ^ ((n >> 1) & 3);
            async16(wbf + (size_t)n * 576 + k0 + c * 8, Bs + s * 8);
        }
        {
            int ks = (k0 >> 3) + cA;
            int ch = (ks >= 24) + (ks >= 48);
            int r = ks - ch * 24;
            int kt = r >> 3, ph = r & 7;
            short8 v8 = (short8){0, 0, 0, 0, 0, 0, 0, 0};
            if (t + kt >= 2)
                v8 = *(const short8*)(xbf + baseA
                        + ((long long)(kt * 3 + ch) << 12) + ph * 64);
            *(short8*)(As + tid * 8) = v8;
        }
        __syncthreads();
        short8 af[4], bf[8];
        #pragma unroll
        for (int mt = 0; mt < 4; mt++) {
            int row = mt * 16 + l16;
            int pc = quad ^ ((row >> 1) & 3);
            af[mt] = *(const short8*)(As + row * 32 + pc * 8);
        }
        #pragma unroll
        for (int nt = 0; nt < 8; nt++) {
            int row = wave * 128 + nt * 16 + l16;
            int pc = quad ^ ((row >> 1) & 3);
            bf[nt] = *(const short8*)(Bs + row * 32 + pc * 8);
        }
        #pragma unroll
        for (int mt = 0; mt < 4; mt++)
            #pragma unroll
            for (int nt = 0; nt < 8; nt++)
                acc[mt][nt] = __builtin_amdgcn_mfma_f32_16x16x32_bf16(
                    af[mt], bf[nt], acc[mt][nt], 0, 0, 0);
        __syncthreads();
    }

    float cbn[8], tgn[8], tbn[8], Gn[8], Ben[8];
    #pragma unroll
    for (int nt = 0; nt < 8; nt++) {
        int n = wave * 128 + nt * 16 + l16;
        cbn[nt] = cb[n]; tgn[nt] = tg[n]; tbn[nt] = tb[n];
        Gn[nt]  = 1.f + 0.5f * gb[bt * 1024 + n];
        Ben[nt] = 0.5f * gb[bt * 1024 + 512 + n];
    }
    #pragma unroll
    for (int mt = 0; mt < 4; mt++)
        #pragma unroll
        for (int reg = 0; reg < 4; reg++) {
            float s = 0.f, ss = 0.f;
            #pragma unroll
            for (int nt = 0; nt < 8; nt++) {
                float v = acc[mt][nt][reg] + cbn[nt];
                s += v; ss += v * v;
            }
            #pragma unroll
            for (int o = 1; o < 16; o <<= 1) {
                s  += __shfl_xor(s, o, 64);
                ss += __shfl_xor(ss, o, 64);
            }
            if (l16 == 0) {
                int m = mt * 16 + quad * 4 + reg;
                redsum[wave][m] = s; redss[wave][m] = ss;
            }
        }
    __syncthreads();
    if (tid < 64) {
        float S  = redsum[0][tid] + redsum[1][tid] + redsum[2][tid] + redsum[3][tid];
        float SS = redss[0][tid] + redss[1][tid] + redss[2][tid] + redss[3][tid];
        float mu = S * (1.f / 512.f);
        float var = SS * (1.f / 512.f) - mu * mu;
        mu_s[tid] = mu; inv_s[tid] = rsqrtf(var + EPS);
    }
    __syncthreads();
    float hacc[8] = {0.f, 0.f, 0.f, 0.f, 0.f, 0.f, 0.f, 0.f};
    #pragma unroll
    for (int mt = 0; mt < 4; mt++)
        #pragma unroll
        for (int reg = 0; reg < 4; reg++) {
            int m = mt * 16 + quad * 4 + reg;
            float mu = mu_s[m], inv = inv_s[m];
            #pragma unroll
            for (int nt = 0; nt < 8; nt++) {
                float v = acc[mt][nt][reg] + cbn[nt];
                hacc[nt] += (v - mu) * inv;
            }
        }
    #pragma unroll
    for (int nt = 0; nt < 8; nt++) {
        hacc[nt] += __shfl_xor(hacc[nt], 16, 64);
        hacc[nt] += __shfl_xor(hacc[nt], 32, 64);
    }
    if (quad == 0)
        #pragma unroll
        for (int nt = 0; nt < 8; nt++) {
            int n = wave * 128 + nt * 16 + l16;
            h[bt * 512 + n] = Gn[nt] * (tgn[nt] * (hacc[nt] * (1.f / 64.f)) + tbn[nt])
                              + Ben[nt];
        }
}

// ---------------------------------------------------------------------------
// Phase A (WGs 0-7): attn head hh + fused proj K-slice. Deep-pipelined:
// kqv uses 4 LDS buffers, issue-3-ahead, counted vmcnt + raw barriers;
// proj weights (both halves) prefetched right after the kqv loop and land
// during the 5 attention stages (lgkm-only barriers keep them in flight).
// LDS map: As 0..32K | Bq 4x12K @32K..80K (kqv) | Ws0 @32K, Ws1 @64K (proj,
// after kqv) | attn overlays in As region | att @96K+2304, pA after.
// ---------------------------------------------------------------------------
__device__ __forceinline__ void attn_proj_phase(
    char* smem, int g, int hh, int tid,
    const float* __restrict__ in, const float* __restrict__ lng,
    const float* __restrict__ lnb, const short* __restrict__ Bw,
    const float* __restrict__ bias, const float* __restrict__ ropeS,
    const float* __restrict__ ropeC, const short* __restrict__ Pw,
    const float* __restrict__ rsPtr, float* __restrict__ tgt) {
    short* As = (short*)smem;                      // 32 KB
    short* Bq = (short*)(smem + 32768);            // 4 x 12288 B
    float (*qsf)[64] = (float(*)[64])(smem);
    float (*ksf)[64] = (float(*)[64])(smem + 8192);
    short* vT  = (short*)(smem + 16384);
    short* qrb = (short*)(smem + 20480);
    short* krb = (short*)(smem + 24576);
    short* yv_s = (short*)(smem + 28672);          // 4 KB, XOR-swizzled
    short* Ws0 = (short*)(smem + 32768);           // proj W half0 (32 KB)
    short* Ws1 = (short*)(smem + 65536);           // proj W half1 (32 KB)
    float (*att)[33] = (float(*)[33])(smem + 98304);
    short* pA  = (short*)(smem + 102528);
    int m0 = g * 32;
    int wave = tid >> 6, lane = tid & 63, quad = lane >> 4, l16 = lane & 15;
    auto issueB = [&](int t) {
        short* dst = Bq + (t & 3) * 6144;
        int k0 = t * 32;
        #pragma unroll
        for (int e = 0; e < 3; e++) {
            int p = e * 256 + tid;
            int row = p >> 2, seg = (p & 3) ^ ((row >> 1) & 3);
            int n = ((row >> 6) << 9) + hh * 64 + (row & 63);
            async16(Bw + (size_t)n * 512 + k0 + seg * 8, dst + p * 8);
        }
    };
    // LN: single read into registers, stats in registers (no LDS, no barrier)
    int rowL = tid >> 3, l8 = tid & 7;
    float hreg[64];
    {
        const float* hp = in + (size_t)(m0 + rowL) * 512 + l8 * 64;
        float s = 0.f, ss = 0.f;
        #pragma unroll
        for (int i2 = 0; i2 < 32; i2++) {
            float2 v = ald2(hp + i2 * 2);
            hreg[i2 * 2] = v.x; hreg[i2 * 2 + 1] = v.y;
            s += v.x + v.y;
            ss += v.x * v.x + v.y * v.y;
        }
        // kqv k-steps 0..2 issued here: older LN loads retire first, so the
        // post-LN counted wait vmcnt(6) leaves exactly t1,t2 in flight.
        issueB(0); issueB(1); issueB(2);
        s += __shfl_xor(s, 1, 64); ss += __shfl_xor(ss, 1, 64);
        s += __shfl_xor(s, 2, 64); ss += __shfl_xor(ss, 2, 64);
        s += __shfl_xor(s, 4, 64); ss += __shfl_xor(ss, 4, 64);
        float mu = s * (1.f / 512.f);
        float inv = rsqrtf(ss * (1.f / 512.f) - mu * mu + EPS);
        #pragma unroll
        for (int j = 0; j < 8; j++) {
            int cc = l8 * 8 + j;
            float4 g0 = *(const float4*)(lng + cc * 8), g1 = *(const float4*)(lng + cc * 8 + 4);
            float4 b0 = *(const float4*)(lnb + cc * 8), b1 = *(const float4*)(lnb + cc * 8 + 4);
            short8 o = {f2bf((hreg[j*8+0] - mu) * inv * g0.x + b0.x),
                        f2bf((hreg[j*8+1] - mu) * inv * g0.y + b0.y),
                        f2bf((hreg[j*8+2] - mu) * inv * g0.z + b0.z),
                        f2bf((hreg[j*8+3] - mu) * inv * g0.w + b0.w),
                        f2bf((hreg[j*8+4] - mu) * inv * g1.x + b1.x),
                        f2bf((hreg[j*8+5] - mu) * inv * g1.y + b1.y),
                        f2bf((hreg[j*8+6] - mu) * inv * g1.z + b1.z),
                        f2bf((hreg[j*8+7] - mu) * inv * g1.w + b1.w)};
            *(short8*)(As + (rowL * 64 + (cc ^ (rowL & 7))) * 8) = o;
        }
    }
    asm volatile("s_waitcnt lgkmcnt(0) vmcnt(6)" ::: "memory");  // t0 + As ready
    S_BARRIER();
    // kqv GEMM: 16 k-steps, 4 buffers, issue 3 ahead, counted waits.
    f32x4 acc[2][3];
    #pragma unroll
    for (int m2 = 0; m2 < 2; m2++)
        #pragma unroll
        for (int gg = 0; gg < 3; gg++) acc[m2][gg] = (f32x4){0.f, 0.f, 0.f, 0.f};
    for (int it = 0; it < 16; it++) {
        if (it < 13) issueB(it + 3);   // overwrites slot read at it-1: safe past barrier(it-1)
        short* Bsc = Bq + (it & 3) * 6144;
        int cc = it * 4 + quad;
        short8 af[2], bf[3];
        #pragma unroll
        for (int m2 = 0; m2 < 2; m2++) {
            int row = m2 * 16 + l16;
            af[m2] = *(const short8*)(As + (row * 64 + (cc ^ (row & 7))) * 8);
        }
        #pragma unroll
        for (int gg = 0; gg < 3; gg++) {
            int row = gg * 64 + wave * 16 + l16;
            int pc = quad ^ ((row >> 1) & 3);
            bf[gg] = *(const short8*)(Bsc + (row * 4 + pc) * 8);
        }
        #pragma unroll
        for (int m2 = 0; m2 < 2; m2++)
            #pragma unroll
            for (int gg = 0; gg < 3; gg++)
                acc[m2][gg] = __builtin_amdgcn_mfma_f32_16x16x32_bf16(
                    af[m2], bf[gg], acc[m2][gg], 0, 0, 0);
        // counted wait: t_{it+1} must be landed; newest loads may remain.
        if (it < 13)       asm volatile("s_waitcnt lgkmcnt(0) vmcnt(6)" ::: "memory");
        else if (it == 13) asm volatile("s_waitcnt lgkmcnt(0) vmcnt(3)" ::: "memory");
        else               asm volatile("s_waitcnt lgkmcnt(0) vmcnt(0)" ::: "memory");
        S_BARRIER();
    }
    // prefetch BOTH proj weight halves now (Bq region dead); they land during
    // the attention stages below (lgkm-only barriers keep them in flight).
    #pragma unroll
    for (int e = 0; e < 8; e++) {
        int p = e * 256 + tid;
        int row = p >> 3, c = p & 7;
        async16(Pw + (size_t)row * 512 + hh * 64 + ((c ^ (row & 7)) * 8), Ws0 + p * 8);
        async16(Pw + (size_t)(256 + row) * 512 + hh * 64 + ((c ^ (row & 7)) * 8), Ws1 + p * 8);
    }
    // epilogue: k,q fp32 -> LDS; v -> vT bf16
    float bb0 = bias[hh * 64 + wave * 16 + l16];
    float bb1 = bias[512 + hh * 64 + wave * 16 + l16];
    float bb2 = bias[1024 + hh * 64 + wave * 16 + l16];
    int dcol = wave * 16 + l16;
    #pragma unroll
    for (int m2 = 0; m2 < 2; m2++)
        #pragma unroll
        for (int reg = 0; reg < 4; reg++) {
            int tkn = m2 * 16 + quad * 4 + reg;
            ksf[tkn][dcol] = acc[m2][0][reg] + bb0;
            qsf[tkn][dcol] = acc[m2][1][reg] + bb1;
            vT[dcol * 32 + (((tkn >> 3) ^ (dcol & 3)) << 3) + (tkn & 7)]
                = f2bf(acc[m2][2][reg] + bb2);
        }
    BAR_LDS();
    // RoPE (table)
    #pragma unroll
    for (int e = 0; e < 8; e++) {
        int idx = e * 256 + tid;
        int t = idx >> 6, d = idx & 63, j = d & 31;
        float sv = ropeS[t * 32 + j], cv = ropeC[t * 32 + j];
        float qv = qsf[t][d], kv = ksf[t][d];
        float qo = qsf[t][d ^ 32], ko = ksf[t][d ^ 32];
        float rq = (d < 32) ? -qo : qo;
        float rk = (d < 32) ? -ko : ko;
        int addr = t * 64 + (((d >> 3) ^ (t & 7)) << 3) + (d & 7);
        qrb[addr] = f2bf(qv * cv + rq * sv);
        krb[addr] = f2bf(kv * cv + rk * sv);
    }
    BAR_LDS();
    int mw = wave & 1, nw = wave >> 1;
    // QK^T via MFMA
    {
        f32x4 sc = (f32x4){0.f, 0.f, 0.f, 0.f};
        #pragma unroll
        for (int kc = 0; kc < 2; kc++) {
            int rq = mw * 16 + l16;
            int rk = nw * 16 + l16;
            short8 aq = *(const short8*)(qrb + rq * 64 + ((((kc << 2) + quad) ^ (rq & 7)) << 3));
            short8 bk = *(const short8*)(krb + rk * 64 + ((((kc << 2) + quad) ^ (rk & 7)) << 3));
            sc = __builtin_amdgcn_mfma_f32_16x16x32_bf16(aq, bk, sc, 0, 0, 0);
        }
        #pragma unroll
        for (int reg = 0; reg < 4; reg++) {
            int qt = mw * 16 + quad * 4 + reg;
            int kt = nw * 16 + l16;
            att[qt][kt] = (kt > qt) ? -1e30f : sc[reg] * 0.125f;
        }
    }
    BAR_LDS();
    // softmax
    {
        int row = tid >> 3, gg = tid & 7;
        float v0 = att[row][gg * 4], v1 = att[row][gg * 4 + 1];
        float v2 = att[row][gg * 4 + 2], v3 = att[row][gg * 4 + 3];
        float mx = fmaxf(fmaxf(v0, v1), fmaxf(v2, v3));
        mx = fmaxf(mx, __shfl_xor(mx, 1, 64));
        mx = fmaxf(mx, __shfl_xor(mx, 2, 64));
        mx = fmaxf(mx, __shfl_xor(mx, 4, 64));
        float e0 = expf(v0 - mx), e1 = expf(v1 - mx);
        float e2 = expf(v2 - mx), e3 = expf(v3 - mx);
        float s = e0 + e1 + e2 + e3;
        s += __shfl_xor(s, 1, 64);
        s += __shfl_xor(s, 2, 64);
        s += __shfl_xor(s, 4, 64);
        float inv = 1.f / s;
        short* pp = pA + row * 32 + gg * 4;
        pp[0] = f2bf(e0 * inv); pp[1] = f2bf(e1 * inv);
        pp[2] = f2bf(e2 * inv); pp[3] = f2bf(e3 * inv);
    }
    BAR_LDS();
    // PV via MFMA -> yv_s (XOR-swizzled)
    {
        int rp = mw * 16 + l16;
        short8 ap = *(const short8*)(pA + rp * 32 + quad * 8);
        #pragma unroll
        for (int i = 0; i < 2; i++) {
            int nt = (wave >> 1) * 2 + i;
            int rv = nt * 16 + l16;
            short8 bv = *(const short8*)(vT + rv * 32 + (((quad ^ (rv & 3))) << 3));
            f32x4 o = (f32x4){0.f, 0.f, 0.f, 0.f};
            o = __builtin_amdgcn_mfma_f32_16x16x32_bf16(ap, bv, o, 0, 0, 0);
            #pragma unroll
            for (int reg = 0; reg < 4; reg++) {
                int t = mw * 16 + quad * 4 + reg;
                int d = nt * 16 + l16;
                yv_s[t * 64 + (d ^ ((t & 7) << 3))] = f2bf(o[reg]);
            }
        }
    }
    BAR_LDS();
    // ---- fused proj: Ws0/Ws1 prefetched long ago -> vmcnt(0) ~ free ----
    float rsv = *rsPtr;
    asm volatile("s_waitcnt vmcnt(0)" ::: "memory");
    __builtin_amdgcn_sched_barrier(0);
    #pragma unroll
    for (int half = 0; half < 2; half++) {
        short* Wsh = half ? Ws1 : Ws0;
        f32x4 pacc[2][4];
        #pragma unroll
        for (int m2 = 0; m2 < 2; m2++)
            #pragma unroll
            for (int nt = 0; nt < 4; nt++) pacc[m2][nt] = (f32x4){0.f, 0.f, 0.f, 0.f};
        #pragma unroll
        for (int kc = 0; kc < 2; kc++) {
            short8 afr[2];
            #pragma unroll
            for (int m2 = 0; m2 < 2; m2++) {
                int ra = m2 * 16 + l16;
                afr[m2] = *(const short8*)(yv_s + ra * 64
                            + (((kc * 4 + quad) ^ (ra & 7)) << 3));
            }
            #pragma unroll
            for (int nt = 0; nt < 4; nt++) {
                int rb = wave * 64 + nt * 16 + l16;
                short8 bfr = *(const short8*)(Wsh + (rb * 8
                            + ((kc * 4 + quad) ^ (rb & 7))) * 8);
                #pragma unroll
                for (int m2 = 0; m2 < 2; m2++)
                    pacc[m2][nt] = __builtin_amdgcn_mfma_f32_16x16x32_bf16(
                        afr[m2], bfr, pacc[m2][nt], 0, 0, 0);
            }
        }
        #pragma unroll
        for (int m2 = 0; m2 < 2; m2++)
            #pragma unroll
            for (int nt = 0; nt < 4; nt++)
                #pragma unroll
                for (int reg = 0; reg < 4; reg++) {
                    int m = m0 + m2 * 16 + quad * 4 + reg;
                    int n = half * 256 + wave * 64 + nt * 16 + l16;
                    atomicAdd(&tgt[(size_t)m * 512 + n], rsv * pacc[m2][nt][reg]);
                }
    }
}

// ---------------------------------------------------------------------------
// Phase A aux (WGs 8-15): residual base + zero duty. Unchanged.
// ---------------------------------------------------------------------------
__device__ __forceinline__ void phaseA_aux(
    int g, int j, int tid,
    const float* __restrict__ in, const float* __restrict__ pb, float rsv,
    float* __restrict__ tgt, float* __restrict__ zz) {
    int m0g = g * 16384;
    {
        float* zp = zz + m0g + j * 2048 + tid * 8;
        astu(zp, 0ull); astu(zp + 2, 0ull); astu(zp + 4, 0ull); astu(zp + 6, 0ull);
    }
    int r = 4 * j + (tid >> 6);
    int c0 = (tid & 63) * 8;
    const float* ip = in + m0g + r * 512 + c0;
    float* tp = tgt + m0g + r * 512 + c0;
    #pragma unroll
    for (int e = 0; e < 4; e++) {
        float2 v = ald2(ip + e * 2);
        atomicAdd(tp + e * 2,     v.x + rsv * pb[c0 + e * 2]);
        atomicAdd(tp + e * 2 + 1, v.y + rsv * pb[c0 + e * 2 + 1]);
    }
}

// ---------------------------------------------------------------------------
// Phase B: LN2 + mlp1(128-slice) + GELU + fused mlp2 K-slice. Pipelined:
// mlp1 uses 3 buffers issue-2-ahead; W2 quarters double-buffered with
// counted waits (16 newest = previous quarter's atomics).
// LDS map: As 0..32K | B1 3x32K @32K..128K | W2 dbuf overlays B1 bufs 0,1 |
// gs 8K @0 (after As dead).
// ---------------------------------------------------------------------------
__device__ __forceinline__ void mlp_phase(
    char* smem, int g, int wgl, int tid,
    const float* __restrict__ in, const float* __restrict__ lng,
    const float* __restrict__ lnb, const short* __restrict__ B1,
    const float* __restrict__ b1, const short* __restrict__ B2,
    const float* __restrict__ b2, const float* __restrict__ rsPtr,
    float* __restrict__ tgt, float* __restrict__ zz) {
    short* As = (short*)smem;                 // 32 KB
    short* B1b = (short*)(smem + 32768);      // 3 x 32 KB
    short* W2b = (short*)(smem + 32768);      // dbuf overlays B1 bufs 0,1
    short* gs = (short*)smem;                 // 8 KB (after As dead)
    int m0 = g * 32, n0 = wgl * 128, m0g = g * 16384;
    int wave = tid >> 6, lane = tid & 63, quad = lane >> 4, l16 = lane & 15;
    float rsv = *rsPtr;
    auto issue1 = [&](int t) {
        short* dst = B1b + (t % 3) * 16384;
        int k0 = t * 128;
        #pragma unroll
        for (int e = 0; e < 8; e++) {
            int p = e * 256 + tid;
            int row = p >> 4, seg = (p & 15) ^ (row & 15);
            async16(B1 + (size_t)(n0 + row) * 512 + k0 + seg * 8, dst + p * 8);
        }
    };
    auto issueW2 = [&](int q) {
        short* dst = W2b + (q & 1) * 16384;
        #pragma unroll
        for (int e = 0; e < 8; e++) {
            int p = e * 256 + tid;
            int row = p >> 4, c = p & 15;
            async16(B2 + (size_t)(q * 128 + row) * 2048 + n0
                        + ((c ^ (row & 15)) * 8), dst + p * 8);
        }
    };
    // aux FIRST (so its vmem ops are oldest): zero duty + residual base
    {
        float* zp = zz + m0g + wgl * 1024 + tid * 4;
        astu(zp, 0ull); astu(zp + 2, 0ull);
    }
    {
        int r = 2 * wgl + (tid >> 7);
        int c0 = (tid & 127) * 4;
        const float* ip = in + m0g + r * 512 + c0;
        float* tp = tgt + m0g + r * 512 + c0;
        #pragma unroll
        for (int e = 0; e < 2; e++) {
            float2 v = ald2(ip + e * 2);
            atomicAdd(tp + e * 2,     v.x + rsv * b2[c0 + e * 2]);
            atomicAdd(tp + e * 2 + 1, v.y + rsv * b2[c0 + e * 2 + 1]);
        }
    }
    // LN: single read, register stats
    int rowL = tid >> 3, l8 = tid & 7;
    float hreg[64];
    {
        const float* hp = in + (size_t)(m0 + rowL) * 512 + l8 * 64;
        float s = 0.f, ss = 0.f;
        #pragma unroll
        for (int i2 = 0; i2 < 32; i2++) {
            float2 v = ald2(hp + i2 * 2);
            hreg[i2 * 2] = v.x; hreg[i2 * 2 + 1] = v.y;
            s += v.x + v.y;
            ss += v.x * v.x + v.y * v.y;
        }
        issue1(0); issue1(1);
        s += __shfl_xor(s, 1, 64); ss += __shfl_xor(ss, 1, 64);
        s += __shfl_xor(s, 2, 64); ss += __shfl_xor(ss, 2, 64);
        s += __shfl_xor(s, 4, 64); ss += __shfl_xor(ss, 4, 64);
        float mu = s * (1.f / 512.f);
        float inv = rsqrtf(ss * (1.f / 512.f) - mu * mu + EPS);
        #pragma unroll
        for (int j = 0; j < 8; j++) {
            int cc = l8 * 8 + j;
            float4 g0 = *(const float4*)(lng + cc * 8), g1 = *(const float4*)(lng + cc * 8 + 4);
            float4 b0 = *(const float4*)(lnb + cc * 8), b1v = *(const float4*)(lnb + cc * 8 + 4);
            short8 o = {f2bf((hreg[j*8+0] - mu) * inv * g0.x + b0.x),
                        f2bf((hreg[j*8+1] - mu) * inv * g0.y + b0.y),
                        f2bf((hreg[j*8+2] - mu) * inv * g0.z + b0.z),
                        f2bf((hreg[j*8+3] - mu) * inv * g0.w + b0.w),
                        f2bf((hreg[j*8+4] - mu) * inv * g1.x + b1v.x),
                        f2bf((hreg[j*8+5] - mu) * inv * g1.y + b1v.y),
                        f2bf((hreg[j*8+6] - mu) * inv * g1.z + b1v.z),
                        f2bf((hreg[j*8+7] - mu) * inv * g1.w + b1v.w)};
            *(short8*)(As + (rowL * 64 + (cc ^ (rowL & 7))) * 8) = o;
        }
    }
    asm volatile("s_waitcnt lgkmcnt(0) vmcnt(8)" ::: "memory");  // t0 + As ready
    S_BARRIER();
    // mlp1: 4 k-steps, 3 buffers, issue 2 ahead
    f32x4 acc[2][2];
    #pragma unroll
    for (int a2 = 0; a2 < 2; a2++)
        #pragma unroll
        for (int b2i = 0; b2i < 2; b2i++) acc[a2][b2i] = (f32x4){0.f, 0.f, 0.f, 0.f};
    for (int it = 0; it < 4; it++) {
        if (it < 2) issue1(it + 2);
        short* Bsc = B1b + (it % 3) * 16384;
        #pragma unroll
        for (int ksub = 0; ksub < 4; ksub++) {
            int ccb = ksub * 4 + quad;
            int cc = it * 16 + ccb;
            short8 af[2], bf[2];
            #pragma unroll
            for (int m2 = 0; m2 < 2; m2++) {
                int row = m2 * 16 + l16;
                af[m2] = *(const short8*)(As + (row * 64 + (cc ^ (row & 7))) * 8);
            }
            #pragma unroll
            for (int n2 = 0; n2 < 2; n2++) {
                int row = wave * 32 + n2 * 16 + l16;
                bf[n2] = *(const short8*)(Bsc + (row * 16 + (ccb ^ (row & 15))) * 8);
            }
            #pragma unroll
            for (int m2 = 0; m2 < 2; m2++)
                #pragma unroll
                for (int n2 = 0; n2 < 2; n2++)
                    acc[m2][n2] = __builtin_amdgcn_mfma_f32_16x16x32_bf16(
                        af[m2], bf[n2], acc[m2][n2], 0, 0, 0);
        }
        if (it < 2)      asm volatile("s_waitcnt lgkmcnt(0) vmcnt(8)" ::: "memory");
        else             asm volatile("s_waitcnt lgkmcnt(0) vmcnt(0)" ::: "memory");
        S_BARRIER();
    }
    // prefetch W2 quarter 0 (B1b buf0 dead past final barrier)
    issueW2(0);
    // GELU -> gs (As region dead)
    #pragma unroll
    for (int m2 = 0; m2 < 2; m2++)
        #pragma unroll
        for (int n2 = 0; n2 < 2; n2++)
            #pragma unroll
            for (int reg = 0; reg < 4; reg++) {
                int mr = m2 * 16 + quad * 4 + reg;
                int nr = wave * 32 + n2 * 16 + l16;
                float v = acc[m2][n2][reg] + b1[n0 + nr];
                v = 0.5f * v * (1.f + erff(v * 0.70710678118f));
                gs[mr * 128 + (nr ^ ((mr & 7) << 3))] = f2bf(v);
            }
    BAR_LDS();   // gs visible; W2_0 still in flight
    // mlp2 quarters: dbuf, counted waits (newest 16 = prev quarter's atomics)
    for (int q = 0; q < 4; q++) {
        if (q == 0) asm volatile("s_waitcnt vmcnt(0)" ::: "memory");
        else        asm volatile("s_waitcnt vmcnt(16)" ::: "memory");
        S_BARRIER();                 // overwrite-safety for the issue below
        if (q < 3) issueW2(q + 1);
        short* W2q = W2b + (q & 1) * 16384;
        f32x4 qacc[2][2];
        #pragma unroll
        for (int m2 = 0; m2 < 2; m2++)
            #pragma unroll
            for (int n2 = 0; n2 < 2; n2++) qacc[m2][n2] = (f32x4){0.f, 0.f, 0.f, 0.f};
        #pragma unroll
        for (int ks = 0; ks < 4; ks++) {
            short8 afr[2];
            #pragma unroll
            for (int m2 = 0; m2 < 2; m2++) {
                int ra = m2 * 16 + l16;
                afr[m2] = *(const short8*)(gs + ra * 128
                            + (((ks * 4 + quad) ^ (ra & 7)) << 3));
            }
            #pragma unroll
            for (int n2 = 0; n2 < 2; n2++) {
                int rb = wave * 32 + n2 * 16 + l16;
                short8 bfr = *(const short8*)(W2q + (rb * 16
                            + ((ks * 4 + quad) ^ (rb & 15))) * 8);
                #pragma unroll
                for (int m2 = 0; m2 < 2; m2++)
                    qacc[m2][n2] = __builtin_amdgcn_mfma_f32_16x16x32_bf16(
                        afr[m2], bfr, qacc[m2][n2], 0, 0, 0);
            }
        }
        #pragma unroll
        for (int m2 = 0; m2 < 2; m2++)
            #pragma unroll
            for (int n2 = 0; n2 < 2; n2++)
                #pragma unroll
                for (int reg = 0; reg < 4; reg++) {
                    int m = m0 + m2 * 16 + quad * 4 + reg;
                    int n = q * 128 + wave * 32 + n2 * 16 + l16;
                    atomicAdd(&tgt[(size_t)m * 512 + n], rsv * qacc[m2][n2][reg]);
                }
    }
}

// ---------------------------------------------------------------------------
__device__ __forceinline__ void head_phase(
    char* smem, int token, int tid,
    const float* __restrict__ h, const float* __restrict__ g,
    const float* __restrict__ bb, const float* __restrict__ w,
    const float* __restrict__ bias0, float* __restrict__ out) {
    float* red = (float*)smem;
    float v0 = ald1(h + (size_t)token * 512 + tid);
    float v1 = ald1(h + (size_t)token * 512 + tid + 256);
    float s  = block_reduce_sum_256(v0 + v1, red);
    float ss = block_reduce_sum_256(v0 * v0 + v1 * v1, red);
    float mu = s * (1.f / 512.f);
    float var = ss * (1.f / 512.f) - mu * mu;
    float inv = rsqrtf(var + EPS);
    float n0 = (v0 - mu) * inv * g[tid] + bb[tid];
    float n1 = (v1 - mu) * inv * g[tid + 256] + bb[tid + 256];
    float dot = block_reduce_sum_256(n0 * w[tid] + n1 * w[tid + 256], red);
    if (tid == 0) out[token] = dot + bias0[0];
}

// ---------------------------------------------------------------------------
// mega v6: R6 structure (16 groups x 16 WGs, 2 fused phases/layer, 3-buffer
// rotation) with deep-pipelined staging: counted vmcnt + raw barriers keep
// weight loads in flight across compute; 128 KB LDS arena.
// ---------------------------------------------------------------------------
__global__ __launch_bounds__(256) void mega(
    float* __restrict__ b0, float* __restrict__ b1p, float* __restrict__ b2p,
    const float* __restrict__ ropeS, const float* __restrict__ ropeC,
    const short* __restrict__ kqvT, const short* __restrict__ projT,
    const short* __restrict__ mlp1T, const short* __restrict__ mlp2T,
    const float* __restrict__ ln1_g, const float* __restrict__ ln1_b,
    const float* __restrict__ kqv_b, const float* __restrict__ proj_b,
    const float* __restrict__ ln2_g, const float* __restrict__ ln2_b,
    const float* __restrict__ mlp_b1, const float* __restrict__ mlp_b2,
    const float* __restrict__ rs_attn, const float* __restrict__ rs_mlp,
    const float* __restrict__ head_g, const float* __restrict__ head_b,
    const float* __restrict__ head_w, const float* __restrict__ head_bs,
    float* __restrict__ out, unsigned* __restrict__ bar) {
    __shared__ char smem[131072] __attribute__((aligned(16)));
    int wg = blockIdx.x, tid = threadIdx.x;
    int g = wg >> 4, wgl = wg & 15;
    unsigned* flag = bar + g * 32;
    unsigned goal = 0;
    float* p0 = b0; float* p1 = b1p; float* p2 = b2p;

    for (int i = 0; i < 6; i++) {
        // ---- Phase A: attn + proj split-K (WGs 0-7) / base + zero (8-15) ----
        if (wgl < 8)
            attn_proj_phase(smem, g, wgl, tid, p0,
                ln1_g + i * 512, ln1_b + i * 512,
                kqvT + (size_t)i * 786432, kqv_b + i * 1536,
                ropeS, ropeC,
                projT + (size_t)i * 262144, rs_attn + i, p1);
        else
            phaseA_aux(g, wgl - 8, tid, p0, proj_b + i * 512, rs_attn[i], p1, p2);
        goal += 16; group_sync(flag, goal);
        // ---- Phase B: LN2 + mlp1 + GELU + mlp2 split-K (all 16 WGs) ----
        mlp_phase(smem, g, wgl, tid, p1,
            ln2_g + i * 512, ln2_b + i * 512,
            mlp1T + (size_t)i * 1048576, mlp_b1 + i * 2048,
            mlp2T + (size_t)i * 1048576, mlp_b2 + i * 512,
            rs_mlp + i, p2, p0);
        goal += 16; group_sync(flag, goal);
        // rotate buffers (period 3)
        float* t = p0; p0 = p2; p2 = p1; p1 = t;
    }
    // ---- head: 2 tokens per WG; result lives in p0 ----
    head_phase(smem, g * 32 + wgl * 2, tid, p0, head_g, head_b, head_w, head_bs, out);
    head_phase(smem, g * 32 + wgl * 2 + 1, tid, p0, head_g, head_b, head_w, head_bs, out);
}

// ---------------------------------------------------------------------------
extern "C" void kernel_launch(void* const* d_in, const int* in_sizes, int n_in,
                              void* d_out, int out_size, void* d_ws, size_t ws_size,
                              hipStream_t stream) {
    const float* x       = (const float*)d_in[0];
    const float* z       = (const float*)d_in[1];
    const float* conv_w  = (const float*)d_in[2];
    const float* conv_b  = (const float*)d_in[3];
    const float* tok_g   = (const float*)d_in[4];
    const float* tok_b   = (const float*)d_in[5];
    const float* film_w  = (const float*)d_in[6];
    const float* film_b  = (const float*)d_in[7];
    const float* ln1_g   = (const float*)d_in[8];
    const float* ln1_b   = (const float*)d_in[9];
    const float* kqv_w   = (const float*)d_in[10];
    const float* kqv_b   = (const float*)d_in[11];
    const float* proj_w  = (const float*)d_in[12];
    const float* proj_b  = (const float*)d_in[13];
    const float* ln2_g   = (const float*)d_in[14];
    const float* ln2_b   = (const float*)d_in[15];
    const float* mlp_w1  = (const float*)d_in[16];
    const float* mlp_b1  = (const float*)d_in[17];
    const float* mlp_w2  = (const float*)d_in[18];
    const float* mlp_b2  = (const float*)d_in[19];
    const float* rs_attn = (const float*)d_in[20];
    const float* rs_mlp  = (const float*)d_in[21];
    const float* head_g  = (const float*)d_in[22];
    const float* head_b  = (const float*)d_in[23];
    const float* head_w  = (const float*)d_in[24];
    const float* head_bs = (const float*)d_in[25];
    float* out = (float*)d_out;

    float* ws = (float*)d_ws;
    float* gb    = ws;                  // 524288 f (FiLM)
    float* h     = gb + 524288;         // 262144 f (buffer R0)
    float* ropeS = h + 262144;          // 1024 f
    float* ropeC = ropeS + 1024;        // 1024 f
    short* sb = (short*)(ropeC + 1024);
    short* wbf   = sb;                 // 294912
    short* kqvT  = wbf   + 294912;     // 4718592
    short* projT = kqvT  + 4718592;    // 1572864
    short* mlp1T = projT + 1572864;    // 6291456
    short* mlp2T = mlp1T + 6291456;    // 6291456
    short* r12   = mlp2T + 6291456;    // 1310720 shorts
    float* R1 = (float*)r12;           // 262144 f
    float* R2 = R1 + 262144;           // 262144 f
    short* xbf   = r12 + 1310720;      // 6291456
    unsigned* bar = (unsigned*)(xbf + 6291456);   // 512 u32

    prep_all<<<23428, 256, 0, stream>>>(
        z, film_w, film_b, gb, conv_w, wbf, x, xbf, ropeS, ropeC,
        kqv_w, kqvT, proj_w, projT, mlp_w1, mlp1T, mlp_w2, mlp2T, bar, R1);

    conv_fused<<<512, 256, 0, stream>>>(xbf, wbf, conv_b, tok_g, tok_b, gb, h);

    mega<<<256, 256, 0, stream>>>(
        h, R1, R2, ropeS, ropeC, kqvT, projT, mlp1T, mlp2T,
        ln1_g, ln1_b, kqv_b, proj_b, ln2_g, ln2_b, mlp_b1, mlp_b2,
        rs_attn, rs_mlp, head_g, head_b, head_w, head_bs, out, bar);
}